// Round 12
// baseline (878.184 us; speedup 1.0000x reference)
//
#include <hip/hip_runtime.h>
#include <math.h>

#define NB 8
#define NC 192
#define NHEADS 8
#define NCF 24
#define NHW 16384
#define NWID 128
#define CQKV 576
#define OQKV_PAD 640
#define CPIN 1024
#define CG 512
#define OM_PAD 256

typedef unsigned short bfu;                 // fp16 bit patterns
typedef _Float16 f16x8 __attribute__((ext_vector_type(8)));
typedef _Float16 f16x2 __attribute__((ext_vector_type(2)));
typedef float f32x4 __attribute__((ext_vector_type(4)));

__device__ __forceinline__ unsigned short f2h(float f) {
    _Float16 h = (_Float16)f;
    return __builtin_bit_cast(unsigned short, h);
}
__device__ __forceinline__ float h2f(unsigned short u) {
    return (float)__builtin_bit_cast(_Float16, u);
}
__device__ __forceinline__ float gelu_tanh(float x) {
    float x3 = x * x * x;
    float z = 0.7978845608028654f * fmaf(0.044715f, x3, x);
    float e = __expf(2.f * z);
    float th = 1.f - 2.f / (e + 1.f);
    return 0.5f * x * (1.f + th);
}

struct F8 { float v[8]; };
union H8 { uint4 u; f16x2 h[4]; };
__device__ __forceinline__ F8 loadh8(const bfu* p) {
    uint4 r = *(const uint4*)p;
    F8 o;
    o.v[0] = h2f((unsigned short)(r.x & 0xffff)); o.v[1] = h2f((unsigned short)(r.x >> 16));
    o.v[2] = h2f((unsigned short)(r.y & 0xffff)); o.v[3] = h2f((unsigned short)(r.y >> 16));
    o.v[4] = h2f((unsigned short)(r.z & 0xffff)); o.v[5] = h2f((unsigned short)(r.z >> 16));
    o.v[6] = h2f((unsigned short)(r.w & 0xffff)); o.v[7] = h2f((unsigned short)(r.w >> 16));
    return o;
}
__device__ __forceinline__ void storeh8(bfu* p, const float* a) {
    uint4 r;
    r.x = (unsigned)f2h(a[0]) | ((unsigned)f2h(a[1]) << 16);
    r.y = (unsigned)f2h(a[2]) | ((unsigned)f2h(a[3]) << 16);
    r.z = (unsigned)f2h(a[4]) | ((unsigned)f2h(a[5]) << 16);
    r.w = (unsigned)f2h(a[6]) | ((unsigned)f2h(a[7]) << 16);
    *(uint4*)p = r;
}
__device__ __forceinline__ f16x2 h2z() {
    f16x2 z; z[0] = (_Float16)0.f; z[1] = (_Float16)0.f; return z;
}
// bijective chunked XCD remap (gridDim.x % 8 == 0)
__device__ __forceinline__ int xcd_swz(int bid, int nblk) {
    return (bid & 7) * (nblk >> 3) + (bid >> 3);
}
// swizzled half-offset within a 192-half (384B) row: slot = 16B chunk idx [0,24)
__device__ __forceinline__ int swz192(int row, int slot) {
    return row * 192 + ((slot >> 3) << 6) + (((slot ^ row) & 7) << 3);
}

__global__ __launch_bounds__(256) void zfill(float* __restrict__ p, int n) {
    int i = blockIdx.x * 256 + threadIdx.x;
    if (i < n) p[i] = 0.f;
}

// ---------------------------------------------------------------------------
// prep_film, wave-parallel. grid (48, NB) x 256.
// ---------------------------------------------------------------------------
__global__ __launch_bounds__(256) void prep_film(
    const float* __restrict__ kv, const float* __restrict__ kern,
    const float* __restrict__ lnw, const float* __restrict__ lnb,
    float* __restrict__ sArr, float* __restrict__ tArr)
{
    const int b = blockIdx.y;
    const int wave = threadIdx.x >> 6, lane = threadIdx.x & 63;
    const int r = blockIdx.x * 4 + wave;
    const float* kvb = kv + b * 256;
    float4 kvv = *(const float4*)(kvb + lane * 4);
    float4 k1 = *(const float4*)(kern + (size_t)r * 256 + lane * 4);
    float4 k2 = *(const float4*)(kern + (size_t)(r + NC) * 256 + lane * 4);
    float d1 = kvv.x * k1.x + kvv.y * k1.y + kvv.z * k1.z + kvv.w * k1.w;
    float d2 = kvv.x * k2.x + kvv.y * k2.y + kvv.z * k2.z + kvv.w * k2.w;
    #pragma unroll
    for (int off = 32; off; off >>= 1) {
        d1 += __shfl_down(d1, off, 64);
        d2 += __shfl_down(d2, off, 64);
    }
    if (lane == 0) {
        sArr[b * NC + r] = lnw[r] * d1;
        tArr[b * NC + r] = lnb[r] * d1 + d2;
    }
}

// ---------------------------------------------------------------------------
// Build fp16 A in MFMA-fragment-packed layout + u, v0. Wave-per-row.
// ---------------------------------------------------------------------------
__global__ __launch_bounds__(256) void wprep(
    const float* __restrict__ W, const float* __restrict__ sA, const float* __restrict__ tA,
    bfu* __restrict__ Abf, float* __restrict__ u, float* __restrict__ v0, int mode)
{
    const int wave = threadIdx.x >> 6, lane = threadIdx.x & 63;
    const int o = blockIdx.x * 4 + wave;
    const int b = blockIdx.y;
    const int Opad = (mode == 0) ? OQKV_PAD : (mode == 1 ? CPIN : OM_PAD);
    const int K = (mode == 2) ? 512 : 192;
    const int Kr = (mode == 2) ? 510 : 192;
    const int K32 = K >> 5;
    int src;
    if (mode == 0) src = (o < 576) ? o : -1;
    else if (mode == 1) src = (o < 510) ? o : (o < 512 ? -1 : (o < 1022 ? o - 2 : -1));
    else src = (o < 192) ? o : -1;
    const float* wr = (src >= 0) ? W + (size_t)src * Kr : nullptr;
    const float* sb = sA + b * NC;
    const float* tb = tA + b * NC;
    bfu* abase = Abf + (size_t)b * Opad * K;
    float au = 0.f, av = 0.f;
    for (int c0 = lane * 4; c0 < K; c0 += 256) {
        float a[4] = {0.f, 0.f, 0.f, 0.f};
        if (src >= 0) {
            #pragma unroll
            for (int j = 0; j < 4; ++j) {
                int c = c0 + j;
                if (c < Kr) {
                    float w = wr[c];
                    if (mode == 2) a[j] = w;
                    else { a[j] = w * sb[c]; av = fmaf(w, tb[c], av); }
                }
            }
        }
        ushort4 pk;
        bfu b0 = f2h(a[0]), b1 = f2h(a[1]), b2 = f2h(a[2]), b3 = f2h(a[3]);
        pk.x = b0; pk.y = b1; pk.z = b2; pk.w = b3;
        au += h2f(b0) + h2f(b1) + h2f(b2) + h2f(b3);
        int frag = (o >> 4) * K32 + (c0 >> 5);
        int within = ((c0 >> 3) & 3) * 128 + (o & 15) * 8 + (c0 & 7);
        *(ushort4*)(abase + (size_t)frag * 512 + within) = pk;
    }
    if (mode < 2) {
        #pragma unroll
        for (int off = 32; off; off >>= 1) {
            au += __shfl_down(au, off, 64);
            av += __shfl_down(av, off, 64);
        }
        if (lane == 0) {
            u[(size_t)b * Opad + o] = au;
            v0[(size_t)b * Opad + o] = (src >= 0) ? av : 0.f;
        }
    }
}

// transpose dw weights to fp16
__global__ __launch_bounds__(256) void wdw_prep(
    const float* __restrict__ src, bfu* __restrict__ dstT, int C, int mode)
{
    int i = blockIdx.x * 256 + threadIdx.x;
    if (i >= 9 * C) return;
    int tap = i / C, col = i % C;
    float v;
    if (mode == 0) v = src[(size_t)col * 9 + tap];
    else {
        if (col < 512) v = (col < 510) ? src[(size_t)col * 9 + tap] : 0.f;
        else { int c2 = col - 512; v = (c2 < 510) ? src[(size_t)(510 + c2) * 9 + tap] : 0.f; }
    }
    dstT[(size_t)tap * C + col] = f2h(v);
}

// ---------------------------------------------------------------------------
// fp16 convert only: channel-major fp32 -> pixel-major fp16 via LDS transpose.
// ---------------------------------------------------------------------------
__global__ __launch_bounds__(256) void ln_cvt_cm(
    const float* __restrict__ x, bfu* __restrict__ xbf, int cb)
{
    __shared__ bfu lt[64][198];
    const int blkpx = blockIdx.x;
    const int b = blkpx >> 8;
    const int n0 = (blkpx & 255) * 64;
    const int tid = threadIdx.x;
    #pragma unroll
    for (int it = 0; it < 12; ++it) {
        int task = it * 256 + tid;
        int c = task >> 4, q = task & 15;
        float4 v = *(const float4*)(x + ((size_t)b * NC + c) * NHW + n0 + q * 4);
        lt[q * 4 + 0][c] = f2h(v.x);
        lt[q * 4 + 1][c] = f2h(v.y);
        lt[q * 4 + 2][c] = f2h(v.z);
        lt[q * 4 + 3][c] = f2h(v.w);
    }
    __syncthreads();
    #pragma unroll
    for (int it = 0; it < 6; ++it) {
        int task = it * 256 + tid;
        int px = task / 24, ckk = task % 24;
        const unsigned* row = (const unsigned*)&lt[px][0];
        uint4 o;
        o.x = row[ckk * 4 + 0]; o.y = row[ckk * 4 + 1];
        o.z = row[ckk * 4 + 2]; o.w = row[ckk * 4 + 3];
        *(uint4*)(xbf + ((size_t)b * NHW + n0 + px) * NC + ckk * 8) = o;
    }
}

// ---------------------------------------------------------------------------
// MFMA GEMM (fp16), A fragment-packed.
// EPI 0/1 (K=192): tile 128o x 128px, single-stage full-K LDS, pitch 192 with
//   XOR-swizzled 16B chunks; EPI 0 computes LN stats IN-KERNEL.
// EPI 3 (K=512): tile 128o x 64px, BK=64 double-buffered; f32 channel-major out.
// ---------------------------------------------------------------------------
template<int EPI>
__global__ __launch_bounds__(256) void gemm_pm(
    const bfu* __restrict__ A, long aBStride, int Opad, int Oreal, int K,
    const bfu* __restrict__ X, int xRow, int xOff,
    void* __restrict__ Y, int yRow,
    const void* __restrict__ res, int resRow,
    const float* __restrict__ uvec, const float* __restrict__ v0vec, int uStride)
{
    constexpr bool FULLK = (EPI != 3);
    constexpr int SMEMSZ = FULLK ? (128 * 192 * 2 + 128 * 8) : 33024;
    __shared__ __align__(16) char smem[SMEMSZ];
    bfu* xs = (bfu*)smem;
    bfu (*stg)[136] = (bfu(*)[136])smem;
    float (*stg32)[129] = (float(*)[129])smem;
    float* smu = (float*)(smem + 128 * 192 * 2);
    float* srs = smu + 128;

    const int b = blockIdx.z;
    const int om = blockIdx.y * 128;
    const int tid = threadIdx.x;
    const int lane = tid & 63, wave = tid >> 6;
    const int wy = wave >> 1, wx = wave & 1;
    const int l15 = lane & 15, kg = lane >> 4;
    const int K32 = K >> 5;
    const int o16b = (om >> 4) + wy * 4;
    const bfu* Ab = A + (size_t)b * aBStride;

    if constexpr (FULLK) {
        const int n0 = blockIdx.x * 128;
        const bfu* Xbase = X + ((size_t)b * NHW + n0) * xRow + xOff;

        f32x4 acc[4][4];
        #pragma unroll
        for (int i = 0; i < 4; ++i)
            #pragma unroll
            for (int j = 0; j < 4; ++j) acc[i][j] = (f32x4){0.f, 0.f, 0.f, 0.f};

        // stage 128 rows x 192 ch, swizzled 16B chunks
        #pragma unroll
        for (int i = 0; i < 12; ++i) {
            int task = i * 256 + tid;
            int r = task / 24, c = task % 24;
            uint4 v = *(const uint4*)(Xbase + (size_t)r * xRow + c * 8);
            *(uint4*)&xs[swz192(r, c)] = v;
        }
        __syncthreads();

        if (EPI == 0) {
            int px = tid >> 1, hh = tid & 1;
            float s = 0.f, ss = 0.f;
            #pragma unroll
            for (int i = 0; i < 12; ++i) {
                int slot = hh * 12 + i;
                F8 v = loadh8(xs + swz192(px, slot));
                #pragma unroll
                for (int j = 0; j < 8; ++j) { s += v.v[j]; ss = fmaf(v.v[j], v.v[j], ss); }
            }
            s += __shfl_xor(s, 1, 64);
            ss += __shfl_xor(ss, 1, 64);
            if (hh == 0) {
                float m = s * (1.f / 192.f);
                float var = ss * (1.f / 192.f) - m * m;
                smu[px] = m;
                srs[px] = rsqrtf(var + 1e-5f);
            }
        }

        #pragma unroll
        for (int k32 = 0; k32 < 6; ++k32) {
            f16x8 af[4], bfr[4];
            #pragma unroll
            for (int mf = 0; mf < 4; ++mf)
                af[mf] = *(const f16x8*)(Ab + ((size_t)(o16b + mf) * 6 + k32) * 512 + lane * 8);
            #pragma unroll
            for (int nf = 0; nf < 4; ++nf) {
                int row = wx * 64 + nf * 16 + l15;
                bfr[nf] = *(const f16x8*)&xs[swz192(row, k32 * 4 + kg)];
            }
            #pragma unroll
            for (int mf = 0; mf < 4; ++mf)
                #pragma unroll
                for (int nf = 0; nf < 4; ++nf)
                    acc[mf][nf] = __builtin_amdgcn_mfma_f32_16x16x32_f16(af[mf], bfr[nf], acc[mf][nf], 0, 0, 0);
        }
        __syncthreads();

        #pragma unroll
        for (int nf = 0; nf < 4; ++nf) {
            const int nl = wx * 64 + nf * 16 + l15;
            float muv = 0.f, rsv = 0.f;
            if (EPI == 0) { muv = smu[nl]; rsv = srs[nl]; }
            #pragma unroll
            for (int mf = 0; mf < 4; ++mf) {
                const int obl = wy * 64 + mf * 16 + kg * 4;
                float r0, r1, r2, r3;
                if (EPI == 0) {
                    float4 uv = *(const float4*)(uvec + (size_t)b * uStride + om + obl);
                    float4 vv = *(const float4*)(v0vec + (size_t)b * uStride + om + obl);
                    r0 = rsv * (acc[mf][nf][0] - muv * uv.x) + vv.x;
                    r1 = rsv * (acc[mf][nf][1] - muv * uv.y) + vv.y;
                    r2 = rsv * (acc[mf][nf][2] - muv * uv.z) + vv.z;
                    r3 = rsv * (acc[mf][nf][3] - muv * uv.w) + vv.w;
                } else {
                    r0 = acc[mf][nf][0]; r1 = acc[mf][nf][1];
                    r2 = acc[mf][nf][2]; r3 = acc[mf][nf][3];
                }
                ushort4 pk;
                pk.x = f2h(r0); pk.y = f2h(r1); pk.z = f2h(r2); pk.w = f2h(r3);
                *(ushort4*)&stg[nl][obl] = pk;
            }
        }
        __syncthreads();

        #pragma unroll
        for (int it = 0; it < 8; ++it) {
            int task = it * 256 + tid;
            int nl = task >> 4, ch = task & 15;
            int oc = om + ch * 8;
            if (oc >= Oreal) continue;
            uint4 sv = *(const uint4*)&stg[nl][ch * 8];
            size_t nglob = (size_t)b * NHW + n0 + nl;
            if (EPI == 0) {
                *(uint4*)((bfu*)Y + nglob * yRow + oc) = sv;
            } else {
                float a[8];
                a[0] = h2f((unsigned short)(sv.x & 0xffff)); a[1] = h2f((unsigned short)(sv.x >> 16));
                a[2] = h2f((unsigned short)(sv.y & 0xffff)); a[3] = h2f((unsigned short)(sv.y >> 16));
                a[4] = h2f((unsigned short)(sv.z & 0xffff)); a[5] = h2f((unsigned short)(sv.z >> 16));
                a[6] = h2f((unsigned short)(sv.w & 0xffff)); a[7] = h2f((unsigned short)(sv.w >> 16));
                F8 rv = loadh8((const bfu*)res + nglob * resRow + oc);
                #pragma unroll
                for (int j = 0; j < 8; ++j) a[j] += rv.v[j];
                storeh8((bfu*)Y + nglob * yRow + oc, a);
            }
        }
    } else {
        const int n0 = blockIdx.x * 64;
        const bfu* Xbase = X + ((size_t)b * NHW + n0) * xRow + xOff;
        const int sr = tid >> 3, sc = tid & 7;
        const int NCH = K >> 6;

        f32x4 acc[4][2];
        #pragma unroll
        for (int i = 0; i < 4; ++i)
            #pragma unroll
            for (int j = 0; j < 2; ++j) acc[i][j] = (f32x4){0.f, 0.f, 0.f, 0.f};

        #pragma unroll
        for (int i = 0; i < 2; ++i) {
            int r = i * 32 + sr;
            uint4 v = *(const uint4*)(Xbase + (size_t)r * xRow + sc * 8);
            *(uint4*)&xs[r * 72 + sc * 8] = v;
        }
        __syncthreads();
        for (int kc = 0; kc < NCH; ++kc) {
            const int cur = kc & 1;
            if (kc + 1 < NCH) {
                #pragma unroll
                for (int i = 0; i < 2; ++i) {
                    int r = i * 32 + sr;
                    uint4 v = *(const uint4*)(Xbase + (size_t)r * xRow + (kc + 1) * 64 + sc * 8);
                    *(uint4*)&xs[((cur ^ 1) * 64 + r) * 72 + sc * 8] = v;
                }
            }
            #pragma unroll
            for (int ks = 0; ks < 2; ++ks) {
                const int k32 = kc * 2 + ks;
                f16x8 af[4], bfr[2];
                #pragma unroll
                for (int mf = 0; mf < 4; ++mf)
                    af[mf] = *(const f16x8*)(Ab + ((size_t)(o16b + mf) * K32 + k32) * 512 + lane * 8);
                #pragma unroll
                for (int nf = 0; nf < 2; ++nf)
                    bfr[nf] = *(const f16x8*)&xs[(cur * 64 + wx * 32 + nf * 16 + l15) * 72 + ks * 32 + kg * 8];
                #pragma unroll
                for (int mf = 0; mf < 4; ++mf)
                    #pragma unroll
                    for (int nf = 0; nf < 2; ++nf)
                        acc[mf][nf] = __builtin_amdgcn_mfma_f32_16x16x32_f16(af[mf], bfr[nf], acc[mf][nf], 0, 0, 0);
            }
            __syncthreads();
        }

        #pragma unroll
        for (int nf = 0; nf < 2; ++nf) {
            const int nl = wx * 32 + nf * 16 + l15;
            #pragma unroll
            for (int mf = 0; mf < 4; ++mf) {
                const int obl = wy * 64 + mf * 16 + kg * 4;
                stg32[nl][obl + 0] = acc[mf][nf][0];
                stg32[nl][obl + 1] = acc[mf][nf][1];
                stg32[nl][obl + 2] = acc[mf][nf][2];
                stg32[nl][obl + 3] = acc[mf][nf][3];
            }
        }
        __syncthreads();

        #pragma unroll
        for (int it = 0; it < 8; ++it) {
            int task = it * 256 + tid;
            int o = task >> 4, q = task & 15;
            int oc = om + o;
            if (oc >= Oreal) continue;
            float vals[4];
            #pragma unroll
            for (int j = 0; j < 4; ++j) {
                float v = stg32[q * 4 + j][o];
                float r = h2f(((const bfu*)res)[((size_t)b * NHW + n0 + q * 4 + j) * resRow + oc]);
                vals[j] = v + r;
            }
            *(float4*)((float*)Y + ((size_t)b * NC + oc) * NHW + n0 + q * 4) =
                make_float4(vals[0], vals[1], vals[2], vals[3]);
        }
    }
}

// ---------------------------------------------------------------------------
// depthwise 3x3, fp16 packed math, thread = 8ch x 8px x 2 ROWS, XCD-swizzled.
// ---------------------------------------------------------------------------
template<int CIN>
__global__ __launch_bounds__(256) void dw_pm8x2(
    const bfu* __restrict__ in, const bfu* __restrict__ wT, bfu* __restrict__ out, int cb)
{
    const int CHUNKS = CIN / 8;
    const int UNITS = NHW / 16;
    const int wid = xcd_swz(blockIdx.x, gridDim.x);
    int f = wid * 256 + threadIdx.x;
    if (f >= cb * UNITS * CHUNKS) return;
    int ch = f % CHUNKS;
    int pu = f / CHUNKS;
    int u = pu % UNITS;
    int b = pu / UNITS;
    int xq = u & 15, yh = u >> 4;
    int x0 = xq * 8, y0 = yh * 2;
    const int c8 = ch * 8;
    const bfu* base = in + ((size_t)b * NHW) * CIN + c8;

    f16x2 w[9][4];
    #pragma unroll
    for (int t = 0; t < 9; ++t) {
        H8 wv; wv.u = *(const uint4*)(wT + (size_t)t * CIN + c8);
        #pragma unroll
        for (int q = 0; q < 4; ++q) w[t][q] = wv.h[q];
    }

    f16x2 acc[2][8][4];
    #pragma unroll
    for (int oy = 0; oy < 2; ++oy)
        #pragma unroll
        for (int j = 0; j < 8; ++j)
            #pragma unroll
            for (int q = 0; q < 4; ++q) acc[oy][j][q] = h2z();

    #pragma unroll
    for (int ry = 0; ry < 4; ++ry) {
        int yy = y0 - 1 + ry;
        if ((unsigned)yy >= (unsigned)NWID) continue;
        const bfu* rb = base + (size_t)yy * NWID * CIN;
        #pragma unroll
        for (int c = 0; c < 10; ++c) {
            int xx = x0 - 1 + c;
            if ((unsigned)xx >= (unsigned)NWID) continue;
            H8 v; v.u = *(const uint4*)(rb + (size_t)xx * CIN);
            #pragma unroll
            for (int oy = 0; oy < 2; ++oy) {
                int rt = ry - oy;
                if (rt < 0 || rt > 2) continue;
                #pragma unroll
                for (int j = 0; j < 8; ++j) {
                    int tx = c - j;
                    if (tx < 0 || tx > 2) continue;
                    #pragma unroll
                    for (int q = 0; q < 4; ++q)
                        acc[oy][j][q] = w[rt * 3 + tx][q] * v.h[q] + acc[oy][j][q];
                }
            }
        }
    }
    #pragma unroll
    for (int oy = 0; oy < 2; ++oy) {
        #pragma unroll
        for (int j = 0; j < 8; ++j) {
            H8 o;
            #pragma unroll
            for (int q = 0; q < 4; ++q) o.h[q] = acc[oy][j][q];
            *(uint4*)(out + ((size_t)b * NHW + (size_t)(y0 + oy) * NWID + x0 + j) * CIN + c8) = o.u;
        }
    }
}

// ---------------------------------------------------------------------------
// depthwise 3x3 + GELU gate, fp16 packed math, thread = 8ch x 8px, XCD-swz.
// ---------------------------------------------------------------------------
template<int CIN, int COUT>
__global__ __launch_bounds__(256) void dw_gate8(
    const bfu* __restrict__ in, const bfu* __restrict__ wT, bfu* __restrict__ out, int cb)
{
    const int CHUNKS = COUT / 8;
    const int NPB = NHW / 8;
    const int wid = xcd_swz(blockIdx.x, gridDim.x);
    int f = wid * 256 + threadIdx.x;
    if (f >= cb * NPB * CHUNKS) return;
    int ch = f % CHUNKS;
    int pb = f / CHUNKS;
    int n8 = pb & (NPB - 1);
    int b  = pb >> 11;
    int xq = n8 & 15, y = n8 >> 4;
    int x0 = xq * 8;
    const int c8 = ch * 8;
    const bfu* rowb = in + ((size_t)b * NHW + (size_t)y * NWID) * CIN + c8;

    f16x2 a1[8][4], a2[8][4];
    #pragma unroll
    for (int j = 0; j < 8; ++j)
        #pragma unroll
        for (int q = 0; q < 4; ++q) { a1[j][q] = h2z(); a2[j][q] = h2z(); }

    #pragma unroll
    for (int dy = -1; dy <= 1; ++dy) {
        int yy = y + dy;
        if ((unsigned)yy >= (unsigned)NWID) continue;
        const bfu* rb = rowb + (long)dy * NWID * CIN;
        f16x2 w1[3][4], w2[3][4];
        #pragma unroll
        for (int t = 0; t < 3; ++t) {
            const bfu* wp = wT + (size_t)((dy + 1) * 3 + t) * CIN + c8;
            H8 wa; wa.u = *(const uint4*)wp;
            H8 wb; wb.u = *(const uint4*)(wp + 512);
            #pragma unroll
            for (int q = 0; q < 4; ++q) { w1[t][q] = wa.h[q]; w2[t][q] = wb.h[q]; }
        }
        #pragma unroll
        for (int c = 0; c < 10; ++c) {
            int xx = x0 - 1 + c;
            if ((unsigned)xx >= (unsigned)NWID) continue;
            H8 v1; v1.u = *(const uint4*)(rb + (size_t)xx * CIN);
            H8 v2; v2.u = *(const uint4*)(rb + (size_t)xx * CIN + 512);
            #pragma unroll
            for (int j = 0; j < 8; ++j) {
                int t = c - j;
                if (t < 0 || t > 2) continue;
                #pragma unroll
                for (int q = 0; q < 4; ++q) {
                    a1[j][q] = w1[t][q] * v1.h[q] + a1[j][q];
                    a2[j][q] = w2[t][q] * v2.h[q] + a2[j][q];
                }
            }
        }
    }
    #pragma unroll
    for (int j = 0; j < 8; ++j) {
        H8 o;
        #pragma unroll
        for (int q = 0; q < 4; ++q) {
            float g0 = gelu_tanh((float)a1[j][q][0]) * (float)a2[j][q][0];
            float g1 = gelu_tanh((float)a1[j][q][1]) * (float)a2[j][q][1];
            f16x2 r; r[0] = (_Float16)g0; r[1] = (_Float16)g1;
            o.h[q] = r;
        }
        *(uint4*)(out + ((size_t)b * NHW + (size_t)y * NWID + x0 + j) * COUT + c8) = o.u;
    }
}

// ---------------------------------------------------------------------------
// MFMA Gram (fp16). grid (64 n-chunks, CB). 4 waves x 2 heads each.
// ---------------------------------------------------------------------------
__global__ __launch_bounds__(256) void gram_pm(
    const bfu* __restrict__ qkv, float* __restrict__ S32,
    float* __restrict__ Q2, float* __restrict__ K2, int b0)
{
    __shared__ bfu lds[392 * 72];
    const int b = blockIdx.y;
    const int nc = blockIdx.x;
    const int tid = threadIdx.x;
    const int lane = tid & 63, wave = tid >> 6;
    const int l15 = lane & 15, kg = lane >> 4;

    f32x4 sAcc[2][2][2], qAcc[2][2], kAcc[2][2];
    #pragma unroll
    for (int h = 0; h < 2; ++h)
        #pragma unroll
        for (int i = 0; i < 2; ++i) {
            qAcc[h][i] = (f32x4){0.f, 0.f, 0.f, 0.f};
            kAcc[h][i] = (f32x4){0.f, 0.f, 0.f, 0.f};
            #pragma unroll
            for (int j = 0; j < 2; ++j) sAcc[h][i][j] = (f32x4){0.f, 0.f, 0.f, 0.f};
        }

    const size_t pbase = (size_t)b * NHW + (size_t)nc * 256;
    unsigned* ldsw = (unsigned*)lds;

    for (int it = 0; it < 4; ++it) {
        const size_t nb = pbase + it * 64;
        #pragma unroll
        for (int i = 0; i < 6; ++i) {
            int task = i * 256 + tid;
            int np = task & 31, ch = task >> 5;
            const bfu* r0 = qkv + (nb + np * 2) * CQKV + ch * 8;
            uint4 v0 = *(const uint4*)r0;
            uint4 v1 = *(const uint4*)(r0 + CQKV);
            int cb8 = ch * 8;
            ldsw[(cb8 + 0) * 36 + np] = (v0.x & 0xffffu) | (v1.x << 16);
            ldsw[(cb8 + 1) * 36 + np] = (v0.x >> 16) | (v1.x & 0xffff0000u);
            ldsw[(cb8 + 2) * 36 + np] = (v0.y & 0xffffu) | (v1.y << 16);
            ldsw[(cb8 + 3) * 36 + np] = (v0.y >> 16) | (v1.y & 0xffff0000u);
            ldsw[(cb8 + 4) * 36 + np] = (v0.z & 0xffffu) | (v1.z << 16);
            ldsw[(cb8 + 5) * 36 + np] = (v0.z >> 16) | (v1.z & 0xffff0000u);
            ldsw[(cb8 + 6) * 36 + np] = (v0.w & 0xffffu) | (v1.w << 16);
            ldsw[(cb8 + 7) * 36 + np] = (v0.w >> 16) | (v1.w & 0xffff0000u);
        }
        ldsw[(384 + (tid >> 5)) * 36 + (tid & 31)] = 0;
        __syncthreads();
        #pragma unroll
        for (int hh = 0; hh < 2; ++hh) {
            const int h = wave * 2 + hh;
            const int qr = h * NCF, kr = NC + h * NCF;
            #pragma unroll
            for (int ks = 0; ks < 2; ++ks) {
                const int nsub = ks * 32 + kg * 8;
                f16x8 aq0 = *(const f16x8*)(lds + (qr + l15) * 72 + nsub);
                f16x8 aq1 = *(const f16x8*)(lds + (qr + 16 + l15) * 72 + nsub);
                f16x8 bk0 = *(const f16x8*)(lds + (kr + l15) * 72 + nsub);
                f16x8 bk1 = *(const f16x8*)(lds + (kr + 16 + l15) * 72 + nsub);
                sAcc[hh][0][0] = __builtin_amdgcn_mfma_f32_16x16x32_f16(aq0, bk0, sAcc[hh][0][0], 0, 0, 0);
                sAcc[hh][0][1] = __builtin_amdgcn_mfma_f32_16x16x32_f16(aq0, bk1, sAcc[hh][0][1], 0, 0, 0);
                sAcc[hh][1][0] = __builtin_amdgcn_mfma_f32_16x16x32_f16(aq1, bk0, sAcc[hh][1][0], 0, 0, 0);
                sAcc[hh][1][1] = __builtin_amdgcn_mfma_f32_16x16x32_f16(aq1, bk1, sAcc[hh][1][1], 0, 0, 0);
                qAcc[hh][0] = __builtin_amdgcn_mfma_f32_16x16x32_f16(aq0, aq0, qAcc[hh][0], 0, 0, 0);
                qAcc[hh][1] = __builtin_amdgcn_mfma_f32_16x16x32_f16(aq1, aq1, qAcc[hh][1], 0, 0, 0);
                kAcc[hh][0] = __builtin_amdgcn_mfma_f32_16x16x32_f16(bk0, bk0, kAcc[hh][0], 0, 0, 0);
                kAcc[hh][1] = __builtin_amdgcn_mfma_f32_16x16x32_f16(bk1, bk1, kAcc[hh][1], 0, 0, 0);
            }
        }
        __syncthreads();
    }

    const int gb = b0 + b;
    #pragma unroll
    for (int hh = 0; hh < 2; ++hh) {
        const int h = wave * 2 + hh;
        float* Sp = S32 + ((size_t)gb * NHEADS + h) * 1024;
        #pragma unroll
        for (int mt = 0; mt < 2; ++mt)
            #pragma unroll
            for (int nt = 0; nt < 2; ++nt)
                #pragma unroll
                for (int r = 0; r < 4; ++r) {
                    int c = mt * 16 + kg * 4 + r, d = nt * 16 + l15;
                    atomicAdd(&Sp[c * 32 + d], sAcc[hh][mt][nt][r]);
                }
        #pragma unroll
        for (int t = 0; t < 2; ++t)
            #pragma unroll
            for (int r = 0; r < 4; ++r) {
                int row = t * 16 + kg * 4 + r, col = t * 16 + l15;
                if (row == col && row < NCF) {
                    atomicAdd(&Q2[((size_t)gb * NHEADS + h) * NCF + row], qAcc[hh][t][r]);
                    atomicAdd(&K2[((size_t)gb * NHEADS + h) * NCF + row], kAcc[hh][t][r]);
                }
            }
    }
}

// ---------------------------------------------------------------------------
// normalize -> softmax -> fold proj_w -> Mbf packed-fragment fp16. grid(CB)
// ---------------------------------------------------------------------------
__global__ __launch_bounds__(256) void attn_fold(
    const float* __restrict__ S32, const float* __restrict__ Q2, const float* __restrict__ K2,
    const float* __restrict__ temp, const float* __restrict__ projw, bfu* __restrict__ Mbf, int b0)
{
    const int gb = b0 + blockIdx.x, tid = threadIdx.x;
    __shared__ float P[NHEADS * NCF * NCF];
    for (int e = tid; e < NHEADS * NCF * NCF; e += 256) {
        int h = e / (NCF * NCF);
        int r = e % (NCF * NCF);
        int c = r / NCF, d = r % NCF;
        float sv = S32[((size_t)gb * NHEADS + h) * 1024 + c * 32 + d];
        float rq = sqrtf(Q2[((size_t)gb * NHEADS + h) * NCF + c]);
        float rk = sqrtf(K2[((size_t)gb * NHEADS + h) * NCF + d]);
        P[e] = sv / (rq * rk) * temp[h];
    }
    __syncthreads();
    if (tid < NHEADS * NCF) {
        int h = tid / NCF, c = tid % NCF;
        float* row = P + h * (NCF * NCF) + c * NCF;
        float mx = row[0];
        #pragma unroll
        for (int d = 1; d < NCF; ++d) mx = fmaxf(mx, row[d]);
        float sum = 0.f;
        #pragma unroll
        for (int d = 0; d < NCF; ++d) { float e2 = __expf(row[d] - mx); row[d] = e2; sum += e2; }
        float inv = 1.f / sum;
        #pragma unroll
        for (int d = 0; d < NCF; ++d) row[d] *= inv;
    }
    __syncthreads();
    bfu* Mb = Mbf + (size_t)gb * OM_PAD * NC;
    if (tid < NC) {
        int o = tid;
        int o16 = o >> 4, l15o = o & 15;
        for (int h = 0; h < NHEADS; ++h) {
            float pw[NCF];
            #pragma unroll
            for (int c = 0; c < NCF; ++c) pw[c] = projw[(size_t)o * NC + h * NCF + c];
            #pragma unroll
            for (int d = 0; d < NCF; ++d) {
                float acc = 0.f;
                #pragma unroll
                for (int c = 0; c < NCF; ++c) acc = fmaf(pw[c], P[h * (NCF * NCF) + c * NCF + d], acc);
                int cc = h * NCF + d;
                int idx = (o16 * 6 + (cc >> 5)) * 512 + ((cc >> 3) & 3) * 128 + l15o * 8 + (cc & 7);
                Mb[idx] = f2h(acc);
            }
        }
    }
    for (int e = tid; e < (OM_PAD - NC) * NC; e += 256) Mb[NC * NC + e] = 0;
}

// ---------------------------------------------------------------------------
extern "C" void kernel_launch(void* const* d_in, const int* in_sizes, int n_in,
                              void* d_out, int out_size, void* d_ws, size_t ws_size,
                              hipStream_t stream)
{
    const float* x     = (const float*)d_in[0];
    const float* kv    = (const float*)d_in[1];
    const float* ln1w  = (const float*)d_in[2];
    const float* ln1b  = (const float*)d_in[3];
    const float* akern = (const float*)d_in[4];
    const float* qkvw  = (const float*)d_in[5];
    const float* qkvdw = (const float*)d_in[6];
    const float* projw = (const float*)d_in[7];
    const float* temp  = (const float*)d_in[8];
    const float* ln2w  = (const float*)d_in[9];
    const float* ln2b  = (const float*)d_in[10];
    const float* fkern = (const float*)d_in[11];
    const float* pinw  = (const float*)d_in[12];
    const float* ffndw = (const float*)d_in[13];
    const float* poutw = (const float*)d_in[14];
    float* out = (float*)d_out;

    char* wp = (char*)d_ws;
    size_t off = 0;
    auto take = [&](size_t bytes) {
        char* r = wp + off;
        off = (off + bytes + 255) & ~(size_t)255;
        return r;
    };
    float* s1 = (float*)take(NB * NC * 4);  float* t1 = (float*)take(NB * NC * 4);
    float* s2 = (float*)take(NB * NC * 4);  float* t2 = (float*)take(NB * NC * 4);
    bfu* A1 = (bfu*)take((size_t)NB * OQKV_PAD * 192 * 2);
    bfu* A2 = (bfu*)take((size_t)NB * CPIN * 192 * 2);
    bfu* A3 = (bfu*)take((size_t)OM_PAD * 512 * 2);
    bfu* Mbf = (bfu*)take((size_t)NB * OM_PAD * NC * 2);
    float* u1  = (float*)take((size_t)NB * OQKV_PAD * 4);
    float* v01 = (float*)take((size_t)NB * OQKV_PAD * 4);
    float* u2  = (float*)take((size_t)NB * CPIN * 4);
    float* v02 = (float*)take((size_t)NB * CPIN * 4);
    bfu* wdwT1 = (bfu*)take(9 * CQKV * 2);
    bfu* wdwT2 = (bfu*)take(9 * CPIN * 2);
    float* S32 = (float*)take((size_t)NB * NHEADS * 1024 * 4);
    float* Q2  = (float*)take((size_t)NB * NHEADS * NCF * 4);
    float* K2  = (float*)take((size_t)NB * NHEADS * NCF * 4);
    const size_t bigoff = off;

    const size_t PB = (size_t)NHW * (384 + 384 + 2048 + 1152);
    size_t avail = (ws_size > bigoff) ? ws_size - bigoff : 0;
    int CB = 8;
    while (CB > 1 && (size_t)CB * PB > avail) CB >>= 1;
    if (CB > 2) CB = 2;   // keep per-phase working set L3-resident (<256 MB)

    dim3 blk(256);

    prep_film<<<dim3(48, NB), blk, 0, stream>>>(kv, akern, ln1w, ln1b, s1, t1);
    prep_film<<<dim3(48, NB), blk, 0, stream>>>(kv, fkern, ln2w, ln2b, s2, t2);
    wprep<<<dim3(OQKV_PAD / 4, NB), blk, 0, stream>>>(qkvw, s1, t1, A1, u1, v01, 0);
    wprep<<<dim3(CPIN / 4, NB), blk, 0, stream>>>(pinw, s2, t2, A2, u2, v02, 1);
    wprep<<<dim3(OM_PAD / 4, 1), blk, 0, stream>>>(poutw, s1, t1, A3, nullptr, nullptr, 2);
    wdw_prep<<<(9 * CQKV + 255) / 256, blk, 0, stream>>>(qkvdw, wdwT1, CQKV, 0);
    wdw_prep<<<(9 * CPIN + 255) / 256, blk, 0, stream>>>(ffndw, wdwT2, CPIN, 1);
    {
        int nz = NB * NHEADS * 1024 + 2 * NB * NHEADS * NCF + 256;
        zfill<<<(nz + 255) / 256, blk, 0, stream>>>(S32, nz);
    }

    for (int b0 = 0; b0 < NB; b0 += CB) {
        bfu* bfX  = (bfu*)(wp + bigoff);
        bfu* out1 = (bfu*)(wp + bigoff + (size_t)CB * NHW * 384);
        char* big1 = wp + bigoff + (size_t)CB * NHW * 768;
        char* big2 = big1 + (size_t)CB * NHW * 2048;
        bfu* qkv_pre = (bfu*)big1;
        bfu* qkvb    = (bfu*)big2;
        bfu* u_pre   = (bfu*)big1;
        bfu* gbuf    = (bfu*)big2;

        const float* xb = x + (size_t)b0 * NC * NHW;

        // ---- attention branch ----
        ln_cvt_cm<<<CB * 256, blk, 0, stream>>>(xb, bfX, CB);
        gemm_pm<0><<<dim3(128, OQKV_PAD / 128, CB), blk, 0, stream>>>(
            A1 + (size_t)b0 * OQKV_PAD * 192, (long)OQKV_PAD * 192, OQKV_PAD, CQKV, 192,
            bfX, NC, 0, qkv_pre, CQKV, nullptr, 0,
            u1 + (size_t)b0 * OQKV_PAD, v01 + (size_t)b0 * OQKV_PAD, OQKV_PAD);
        dw_pm8x2<CQKV><<<CB * 288, blk, 0, stream>>>(qkv_pre, wdwT1, qkvb, CB);
        gram_pm<<<dim3(64, CB), blk, 0, stream>>>(qkvb, S32, Q2, K2, b0);
        attn_fold<<<CB, blk, 0, stream>>>(S32, Q2, K2, temp, projw, Mbf, b0);
        // out1(fp16) = bfX + M @ v
        gemm_pm<1><<<dim3(128, OM_PAD / 128, CB), blk, 0, stream>>>(
            Mbf + (size_t)b0 * OM_PAD * NC, (long)OM_PAD * NC, OM_PAD, NC, 192,
            qkvb, CQKV, 384, out1, NC, bfX, NC,
            nullptr, nullptr, 0);

        // ---- FFN branch ----
        gemm_pm<0><<<dim3(128, CPIN / 128, CB), blk, 0, stream>>>(
            A2 + (size_t)b0 * CPIN * 192, (long)CPIN * 192, CPIN, CPIN, 192,
            out1, NC, 0, u_pre, CPIN, nullptr, 0,
            u2 + (size_t)b0 * CPIN, v02 + (size_t)b0 * CPIN, CPIN);
        dw_gate8<CPIN, CG><<<CB * 512, blk, 0, stream>>>(u_pre, wdwT2, gbuf, CB);
        // d_out (f32 channel-major) = out1 + pout @ g, written directly
        gemm_pm<3><<<dim3(256, OM_PAD / 128, CB), blk, 0, stream>>>(
            A3, 0, OM_PAD, NC, 512,
            gbuf, CG, 0, out + (size_t)b0 * NC * NHW, 0, out1, NC,
            nullptr, nullptr, 0);
    }
}

// Round 13
// 751.963 us; speedup vs baseline: 1.1679x; 1.1679x over previous
//
#include <hip/hip_runtime.h>
#include <math.h>

#define NB 8
#define NC 192
#define NHEADS 8
#define NCF 24
#define NHW 16384
#define NWID 128
#define CQKV 576
#define OQKV_PAD 640
#define CPIN 1024
#define CG 512
#define OM_PAD 256

typedef unsigned short bfu;                 // fp16 bit patterns
typedef _Float16 f16x8 __attribute__((ext_vector_type(8)));
typedef _Float16 f16x2 __attribute__((ext_vector_type(2)));
typedef float f32x4 __attribute__((ext_vector_type(4)));

__device__ __forceinline__ unsigned short f2h(float f) {
    _Float16 h = (_Float16)f;
    return __builtin_bit_cast(unsigned short, h);
}
__device__ __forceinline__ float h2f(unsigned short u) {
    return (float)__builtin_bit_cast(_Float16, u);
}
__device__ __forceinline__ float gelu_tanh(float x) {
    float x3 = x * x * x;
    float z = 0.7978845608028654f * fmaf(0.044715f, x3, x);
    float e = __expf(2.f * z);
    float th = 1.f - 2.f / (e + 1.f);
    return 0.5f * x * (1.f + th);
}

struct F8 { float v[8]; };
union H8 { uint4 u; f16x2 h[4]; };
__device__ __forceinline__ F8 loadh8(const bfu* p) {
    uint4 r = *(const uint4*)p;
    F8 o;
    o.v[0] = h2f((unsigned short)(r.x & 0xffff)); o.v[1] = h2f((unsigned short)(r.x >> 16));
    o.v[2] = h2f((unsigned short)(r.y & 0xffff)); o.v[3] = h2f((unsigned short)(r.y >> 16));
    o.v[4] = h2f((unsigned short)(r.z & 0xffff)); o.v[5] = h2f((unsigned short)(r.z >> 16));
    o.v[6] = h2f((unsigned short)(r.w & 0xffff)); o.v[7] = h2f((unsigned short)(r.w >> 16));
    return o;
}
__device__ __forceinline__ void storeh8(bfu* p, const float* a) {
    uint4 r;
    r.x = (unsigned)f2h(a[0]) | ((unsigned)f2h(a[1]) << 16);
    r.y = (unsigned)f2h(a[2]) | ((unsigned)f2h(a[3]) << 16);
    r.z = (unsigned)f2h(a[4]) | ((unsigned)f2h(a[5]) << 16);
    r.w = (unsigned)f2h(a[6]) | ((unsigned)f2h(a[7]) << 16);
    *(uint4*)p = r;
}
__device__ __forceinline__ f16x2 h2z() {
    f16x2 z; z[0] = (_Float16)0.f; z[1] = (_Float16)0.f; return z;
}
// bijective chunked XCD remap (gridDim.x % 8 == 0)
__device__ __forceinline__ int xcd_swz(int bid, int nblk) {
    return (bid & 7) * (nblk >> 3) + (bid >> 3);
}
// swizzled half-offset within a 192-half (384B) row: slot = 16B chunk idx [0,24)
__device__ __forceinline__ int swz192(int row, int slot) {
    return row * 192 + ((slot >> 3) << 6) + (((slot ^ row) & 7) << 3);
}

__global__ __launch_bounds__(256) void zfill(float* __restrict__ p, int n) {
    int i = blockIdx.x * 256 + threadIdx.x;
    if (i < n) p[i] = 0.f;
}

// ---------------------------------------------------------------------------
// prep_film, wave-parallel. grid (48, NB) x 256.
// ---------------------------------------------------------------------------
__global__ __launch_bounds__(256) void prep_film(
    const float* __restrict__ kv, const float* __restrict__ kern,
    const float* __restrict__ lnw, const float* __restrict__ lnb,
    float* __restrict__ sArr, float* __restrict__ tArr)
{
    const int b = blockIdx.y;
    const int wave = threadIdx.x >> 6, lane = threadIdx.x & 63;
    const int r = blockIdx.x * 4 + wave;
    const float* kvb = kv + b * 256;
    float4 kvv = *(const float4*)(kvb + lane * 4);
    float4 k1 = *(const float4*)(kern + (size_t)r * 256 + lane * 4);
    float4 k2 = *(const float4*)(kern + (size_t)(r + NC) * 256 + lane * 4);
    float d1 = kvv.x * k1.x + kvv.y * k1.y + kvv.z * k1.z + kvv.w * k1.w;
    float d2 = kvv.x * k2.x + kvv.y * k2.y + kvv.z * k2.z + kvv.w * k2.w;
    #pragma unroll
    for (int off = 32; off; off >>= 1) {
        d1 += __shfl_down(d1, off, 64);
        d2 += __shfl_down(d2, off, 64);
    }
    if (lane == 0) {
        sArr[b * NC + r] = lnw[r] * d1;
        tArr[b * NC + r] = lnb[r] * d1 + d2;
    }
}

// ---------------------------------------------------------------------------
// Build fp16 A in MFMA-fragment-packed layout + u, v0. Wave-per-row.
// ---------------------------------------------------------------------------
__global__ __launch_bounds__(256) void wprep(
    const float* __restrict__ W, const float* __restrict__ sA, const float* __restrict__ tA,
    bfu* __restrict__ Abf, float* __restrict__ u, float* __restrict__ v0, int mode)
{
    const int wave = threadIdx.x >> 6, lane = threadIdx.x & 63;
    const int o = blockIdx.x * 4 + wave;
    const int b = blockIdx.y;
    const int Opad = (mode == 0) ? OQKV_PAD : (mode == 1 ? CPIN : OM_PAD);
    const int K = (mode == 2) ? 512 : 192;
    const int Kr = (mode == 2) ? 510 : 192;
    const int K32 = K >> 5;
    int src;
    if (mode == 0) src = (o < 576) ? o : -1;
    else if (mode == 1) src = (o < 510) ? o : (o < 512 ? -1 : (o < 1022 ? o - 2 : -1));
    else src = (o < 192) ? o : -1;
    const float* wr = (src >= 0) ? W + (size_t)src * Kr : nullptr;
    const float* sb = sA + b * NC;
    const float* tb = tA + b * NC;
    bfu* abase = Abf + (size_t)b * Opad * K;
    float au = 0.f, av = 0.f;
    for (int c0 = lane * 4; c0 < K; c0 += 256) {
        float a[4] = {0.f, 0.f, 0.f, 0.f};
        if (src >= 0) {
            #pragma unroll
            for (int j = 0; j < 4; ++j) {
                int c = c0 + j;
                if (c < Kr) {
                    float w = wr[c];
                    if (mode == 2) a[j] = w;
                    else { a[j] = w * sb[c]; av = fmaf(w, tb[c], av); }
                }
            }
        }
        ushort4 pk;
        bfu b0 = f2h(a[0]), b1 = f2h(a[1]), b2 = f2h(a[2]), b3 = f2h(a[3]);
        pk.x = b0; pk.y = b1; pk.z = b2; pk.w = b3;
        au += h2f(b0) + h2f(b1) + h2f(b2) + h2f(b3);
        int frag = (o >> 4) * K32 + (c0 >> 5);
        int within = ((c0 >> 3) & 3) * 128 + (o & 15) * 8 + (c0 & 7);
        *(ushort4*)(abase + (size_t)frag * 512 + within) = pk;
    }
    if (mode < 2) {
        #pragma unroll
        for (int off = 32; off; off >>= 1) {
            au += __shfl_down(au, off, 64);
            av += __shfl_down(av, off, 64);
        }
        if (lane == 0) {
            u[(size_t)b * Opad + o] = au;
            v0[(size_t)b * Opad + o] = (src >= 0) ? av : 0.f;
        }
    }
}

// transpose dw weights to fp16
__global__ __launch_bounds__(256) void wdw_prep(
    const float* __restrict__ src, bfu* __restrict__ dstT, int C, int mode)
{
    int i = blockIdx.x * 256 + threadIdx.x;
    if (i >= 9 * C) return;
    int tap = i / C, col = i % C;
    float v;
    if (mode == 0) v = src[(size_t)col * 9 + tap];
    else {
        if (col < 512) v = (col < 510) ? src[(size_t)col * 9 + tap] : 0.f;
        else { int c2 = col - 512; v = (c2 < 510) ? src[(size_t)(510 + c2) * 9 + tap] : 0.f; }
    }
    dstT[(size_t)tap * C + col] = f2h(v);
}

// ---------------------------------------------------------------------------
// fp16 convert only: channel-major fp32 -> pixel-major fp16 via LDS transpose.
// ---------------------------------------------------------------------------
__global__ __launch_bounds__(256) void ln_cvt_cm(
    const float* __restrict__ x, bfu* __restrict__ xbf, int cb)
{
    __shared__ bfu lt[64][198];
    const int blkpx = blockIdx.x;
    const int b = blkpx >> 8;
    const int n0 = (blkpx & 255) * 64;
    const int tid = threadIdx.x;
    #pragma unroll
    for (int it = 0; it < 12; ++it) {
        int task = it * 256 + tid;
        int c = task >> 4, q = task & 15;
        float4 v = *(const float4*)(x + ((size_t)b * NC + c) * NHW + n0 + q * 4);
        lt[q * 4 + 0][c] = f2h(v.x);
        lt[q * 4 + 1][c] = f2h(v.y);
        lt[q * 4 + 2][c] = f2h(v.z);
        lt[q * 4 + 3][c] = f2h(v.w);
    }
    __syncthreads();
    #pragma unroll
    for (int it = 0; it < 6; ++it) {
        int task = it * 256 + tid;
        int px = task / 24, ckk = task % 24;
        const unsigned* row = (const unsigned*)&lt[px][0];
        uint4 o;
        o.x = row[ckk * 4 + 0]; o.y = row[ckk * 4 + 1];
        o.z = row[ckk * 4 + 2]; o.w = row[ckk * 4 + 3];
        *(uint4*)(xbf + ((size_t)b * NHW + n0 + px) * NC + ckk * 8) = o;
    }
}

// ---------------------------------------------------------------------------
// MFMA GEMM (fp16), A fragment-packed.
// EPI 0/1 (K=192): tile 128o x 128px, single-stage full-K LDS, pitch 192 with
//   XOR-swizzled 16B chunks; EPI 0 computes LN stats IN-KERNEL.
// EPI 3 (K=512): tile 128o x 64px, BK=64 double-buffered; f32 channel-major out.
// ---------------------------------------------------------------------------
template<int EPI>
__global__ __launch_bounds__(256) void gemm_pm(
    const bfu* __restrict__ A, long aBStride, int Opad, int Oreal, int K,
    const bfu* __restrict__ X, int xRow, int xOff,
    void* __restrict__ Y, int yRow,
    const void* __restrict__ res, int resRow,
    const float* __restrict__ uvec, const float* __restrict__ v0vec, int uStride)
{
    constexpr bool FULLK = (EPI != 3);
    constexpr int SMEMSZ = FULLK ? (128 * 192 * 2 + 128 * 8) : 33024;
    __shared__ __align__(16) char smem[SMEMSZ];
    bfu* xs = (bfu*)smem;
    bfu (*stg)[136] = (bfu(*)[136])smem;
    float (*stg32)[129] = (float(*)[129])smem;
    float* smu = (float*)(smem + 128 * 192 * 2);
    float* srs = smu + 128;

    const int b = blockIdx.z;
    const int om = blockIdx.y * 128;
    const int tid = threadIdx.x;
    const int lane = tid & 63, wave = tid >> 6;
    const int wy = wave >> 1, wx = wave & 1;
    const int l15 = lane & 15, kg = lane >> 4;
    const int K32 = K >> 5;
    const int o16b = (om >> 4) + wy * 4;
    const bfu* Ab = A + (size_t)b * aBStride;

    if constexpr (FULLK) {
        const int n0 = blockIdx.x * 128;
        const bfu* Xbase = X + ((size_t)b * NHW + n0) * xRow + xOff;

        f32x4 acc[4][4];
        #pragma unroll
        for (int i = 0; i < 4; ++i)
            #pragma unroll
            for (int j = 0; j < 4; ++j) acc[i][j] = (f32x4){0.f, 0.f, 0.f, 0.f};

        // stage 128 rows x 192 ch, swizzled 16B chunks
        #pragma unroll
        for (int i = 0; i < 12; ++i) {
            int task = i * 256 + tid;
            int r = task / 24, c = task % 24;
            uint4 v = *(const uint4*)(Xbase + (size_t)r * xRow + c * 8);
            *(uint4*)&xs[swz192(r, c)] = v;
        }
        __syncthreads();

        if (EPI == 0) {
            int px = tid >> 1, hh = tid & 1;
            float s = 0.f, ss = 0.f;
            #pragma unroll
            for (int i = 0; i < 12; ++i) {
                int slot = hh * 12 + i;
                F8 v = loadh8(xs + swz192(px, slot));
                #pragma unroll
                for (int j = 0; j < 8; ++j) { s += v.v[j]; ss = fmaf(v.v[j], v.v[j], ss); }
            }
            s += __shfl_xor(s, 1, 64);
            ss += __shfl_xor(ss, 1, 64);
            if (hh == 0) {
                float m = s * (1.f / 192.f);
                float var = ss * (1.f / 192.f) - m * m;
                smu[px] = m;
                srs[px] = rsqrtf(var + 1e-5f);
            }
        }

        #pragma unroll
        for (int k32 = 0; k32 < 6; ++k32) {
            f16x8 af[4], bfr[4];
            #pragma unroll
            for (int mf = 0; mf < 4; ++mf)
                af[mf] = *(const f16x8*)(Ab + ((size_t)(o16b + mf) * 6 + k32) * 512 + lane * 8);
            #pragma unroll
            for (int nf = 0; nf < 4; ++nf) {
                int row = wx * 64 + nf * 16 + l15;
                bfr[nf] = *(const f16x8*)&xs[swz192(row, k32 * 4 + kg)];
            }
            #pragma unroll
            for (int mf = 0; mf < 4; ++mf)
                #pragma unroll
                for (int nf = 0; nf < 4; ++nf)
                    acc[mf][nf] = __builtin_amdgcn_mfma_f32_16x16x32_f16(af[mf], bfr[nf], acc[mf][nf], 0, 0, 0);
        }
        __syncthreads();

        #pragma unroll
        for (int nf = 0; nf < 4; ++nf) {
            const int nl = wx * 64 + nf * 16 + l15;
            float muv = 0.f, rsv = 0.f;
            if (EPI == 0) { muv = smu[nl]; rsv = srs[nl]; }
            #pragma unroll
            for (int mf = 0; mf < 4; ++mf) {
                const int obl = wy * 64 + mf * 16 + kg * 4;
                float r0, r1, r2, r3;
                if (EPI == 0) {
                    float4 uv = *(const float4*)(uvec + (size_t)b * uStride + om + obl);
                    float4 vv = *(const float4*)(v0vec + (size_t)b * uStride + om + obl);
                    r0 = rsv * (acc[mf][nf][0] - muv * uv.x) + vv.x;
                    r1 = rsv * (acc[mf][nf][1] - muv * uv.y) + vv.y;
                    r2 = rsv * (acc[mf][nf][2] - muv * uv.z) + vv.z;
                    r3 = rsv * (acc[mf][nf][3] - muv * uv.w) + vv.w;
                } else {
                    r0 = acc[mf][nf][0]; r1 = acc[mf][nf][1];
                    r2 = acc[mf][nf][2]; r3 = acc[mf][nf][3];
                }
                ushort4 pk;
                pk.x = f2h(r0); pk.y = f2h(r1); pk.z = f2h(r2); pk.w = f2h(r3);
                *(ushort4*)&stg[nl][obl] = pk;
            }
        }
        __syncthreads();

        #pragma unroll
        for (int it = 0; it < 8; ++it) {
            int task = it * 256 + tid;
            int nl = task >> 4, ch = task & 15;
            int oc = om + ch * 8;
            if (oc >= Oreal) continue;
            uint4 sv = *(const uint4*)&stg[nl][ch * 8];
            size_t nglob = (size_t)b * NHW + n0 + nl;
            if (EPI == 0) {
                *(uint4*)((bfu*)Y + nglob * yRow + oc) = sv;
            } else {
                float a[8];
                a[0] = h2f((unsigned short)(sv.x & 0xffff)); a[1] = h2f((unsigned short)(sv.x >> 16));
                a[2] = h2f((unsigned short)(sv.y & 0xffff)); a[3] = h2f((unsigned short)(sv.y >> 16));
                a[4] = h2f((unsigned short)(sv.z & 0xffff)); a[5] = h2f((unsigned short)(sv.z >> 16));
                a[6] = h2f((unsigned short)(sv.w & 0xffff)); a[7] = h2f((unsigned short)(sv.w >> 16));
                F8 rv = loadh8((const bfu*)res + nglob * resRow + oc);
                #pragma unroll
                for (int j = 0; j < 8; ++j) a[j] += rv.v[j];
                storeh8((bfu*)Y + nglob * yRow + oc, a);
            }
        }
    } else {
        const int n0 = blockIdx.x * 64;
        const bfu* Xbase = X + ((size_t)b * NHW + n0) * xRow + xOff;
        const int sr = tid >> 3, sc = tid & 7;
        const int NCH = K >> 6;

        f32x4 acc[4][2];
        #pragma unroll
        for (int i = 0; i < 4; ++i)
            #pragma unroll
            for (int j = 0; j < 2; ++j) acc[i][j] = (f32x4){0.f, 0.f, 0.f, 0.f};

        #pragma unroll
        for (int i = 0; i < 2; ++i) {
            int r = i * 32 + sr;
            uint4 v = *(const uint4*)(Xbase + (size_t)r * xRow + sc * 8);
            *(uint4*)&xs[r * 72 + sc * 8] = v;
        }
        __syncthreads();
        for (int kc = 0; kc < NCH; ++kc) {
            const int cur = kc & 1;
            if (kc + 1 < NCH) {
                #pragma unroll
                for (int i = 0; i < 2; ++i) {
                    int r = i * 32 + sr;
                    uint4 v = *(const uint4*)(Xbase + (size_t)r * xRow + (kc + 1) * 64 + sc * 8);
                    *(uint4*)&xs[((cur ^ 1) * 64 + r) * 72 + sc * 8] = v;
                }
            }
            #pragma unroll
            for (int ks = 0; ks < 2; ++ks) {
                const int k32 = kc * 2 + ks;
                f16x8 af[4], bfr[2];
                #pragma unroll
                for (int mf = 0; mf < 4; ++mf)
                    af[mf] = *(const f16x8*)(Ab + ((size_t)(o16b + mf) * K32 + k32) * 512 + lane * 8);
                #pragma unroll
                for (int nf = 0; nf < 2; ++nf)
                    bfr[nf] = *(const f16x8*)&xs[(cur * 64 + wx * 32 + nf * 16 + l15) * 72 + ks * 32 + kg * 8];
                #pragma unroll
                for (int mf = 0; mf < 4; ++mf)
                    #pragma unroll
                    for (int nf = 0; nf < 2; ++nf)
                        acc[mf][nf] = __builtin_amdgcn_mfma_f32_16x16x32_f16(af[mf], bfr[nf], acc[mf][nf], 0, 0, 0);
            }
            __syncthreads();
        }

        #pragma unroll
        for (int nf = 0; nf < 2; ++nf) {
            const int nl = wx * 32 + nf * 16 + l15;
            #pragma unroll
            for (int mf = 0; mf < 4; ++mf) {
                const int obl = wy * 64 + mf * 16 + kg * 4;
                stg32[nl][obl + 0] = acc[mf][nf][0];
                stg32[nl][obl + 1] = acc[mf][nf][1];
                stg32[nl][obl + 2] = acc[mf][nf][2];
                stg32[nl][obl + 3] = acc[mf][nf][3];
            }
        }
        __syncthreads();

        #pragma unroll
        for (int it = 0; it < 8; ++it) {
            int task = it * 256 + tid;
            int o = task >> 4, q = task & 15;
            int oc = om + o;
            if (oc >= Oreal) continue;
            float vals[4];
            #pragma unroll
            for (int j = 0; j < 4; ++j) {
                float v = stg32[q * 4 + j][o];
                float r = h2f(((const bfu*)res)[((size_t)b * NHW + n0 + q * 4 + j) * resRow + oc]);
                vals[j] = v + r;
            }
            *(float4*)((float*)Y + ((size_t)b * NC + oc) * NHW + n0 + q * 4) =
                make_float4(vals[0], vals[1], vals[2], vals[3]);
        }
    }
}

// ---------------------------------------------------------------------------
// depthwise 3x3, fp16 packed math, thread = 8ch x 8px x 2 ROWS, XCD-swizzled.
// ---------------------------------------------------------------------------
template<int CIN>
__global__ __launch_bounds__(256) void dw_pm8x2(
    const bfu* __restrict__ in, const bfu* __restrict__ wT, bfu* __restrict__ out, int cb)
{
    const int CHUNKS = CIN / 8;
    const int UNITS = NHW / 16;
    const int wid = xcd_swz(blockIdx.x, gridDim.x);
    int f = wid * 256 + threadIdx.x;
    if (f >= cb * UNITS * CHUNKS) return;
    int ch = f % CHUNKS;
    int pu = f / CHUNKS;
    int u = pu % UNITS;
    int b = pu / UNITS;
    int xq = u & 15, yh = u >> 4;
    int x0 = xq * 8, y0 = yh * 2;
    const int c8 = ch * 8;
    const bfu* base = in + ((size_t)b * NHW) * CIN + c8;

    f16x2 w[9][4];
    #pragma unroll
    for (int t = 0; t < 9; ++t) {
        H8 wv; wv.u = *(const uint4*)(wT + (size_t)t * CIN + c8);
        #pragma unroll
        for (int q = 0; q < 4; ++q) w[t][q] = wv.h[q];
    }

    f16x2 acc[2][8][4];
    #pragma unroll
    for (int oy = 0; oy < 2; ++oy)
        #pragma unroll
        for (int j = 0; j < 8; ++j)
            #pragma unroll
            for (int q = 0; q < 4; ++q) acc[oy][j][q] = h2z();

    #pragma unroll
    for (int ry = 0; ry < 4; ++ry) {
        int yy = y0 - 1 + ry;
        if ((unsigned)yy >= (unsigned)NWID) continue;
        const bfu* rb = base + (size_t)yy * NWID * CIN;
        #pragma unroll
        for (int c = 0; c < 10; ++c) {
            int xx = x0 - 1 + c;
            if ((unsigned)xx >= (unsigned)NWID) continue;
            H8 v; v.u = *(const uint4*)(rb + (size_t)xx * CIN);
            #pragma unroll
            for (int oy = 0; oy < 2; ++oy) {
                int rt = ry - oy;
                if (rt < 0 || rt > 2) continue;
                #pragma unroll
                for (int j = 0; j < 8; ++j) {
                    int tx = c - j;
                    if (tx < 0 || tx > 2) continue;
                    #pragma unroll
                    for (int q = 0; q < 4; ++q)
                        acc[oy][j][q] = w[rt * 3 + tx][q] * v.h[q] + acc[oy][j][q];
                }
            }
        }
    }
    #pragma unroll
    for (int oy = 0; oy < 2; ++oy) {
        #pragma unroll
        for (int j = 0; j < 8; ++j) {
            H8 o;
            #pragma unroll
            for (int q = 0; q < 4; ++q) o.h[q] = acc[oy][j][q];
            *(uint4*)(out + ((size_t)b * NHW + (size_t)(y0 + oy) * NWID + x0 + j) * CIN + c8) = o.u;
        }
    }
}

// ---------------------------------------------------------------------------
// depthwise 3x3 + GELU gate, fp16 packed math, thread = 8ch x 8px, XCD-swz.
// ---------------------------------------------------------------------------
template<int CIN, int COUT>
__global__ __launch_bounds__(256) void dw_gate8(
    const bfu* __restrict__ in, const bfu* __restrict__ wT, bfu* __restrict__ out, int cb)
{
    const int CHUNKS = COUT / 8;
    const int NPB = NHW / 8;
    const int wid = xcd_swz(blockIdx.x, gridDim.x);
    int f = wid * 256 + threadIdx.x;
    if (f >= cb * NPB * CHUNKS) return;
    int ch = f % CHUNKS;
    int pb = f / CHUNKS;
    int n8 = pb & (NPB - 1);
    int b  = pb >> 11;
    int xq = n8 & 15, y = n8 >> 4;
    int x0 = xq * 8;
    const int c8 = ch * 8;
    const bfu* rowb = in + ((size_t)b * NHW + (size_t)y * NWID) * CIN + c8;

    f16x2 a1[8][4], a2[8][4];
    #pragma unroll
    for (int j = 0; j < 8; ++j)
        #pragma unroll
        for (int q = 0; q < 4; ++q) { a1[j][q] = h2z(); a2[j][q] = h2z(); }

    #pragma unroll
    for (int dy = -1; dy <= 1; ++dy) {
        int yy = y + dy;
        if ((unsigned)yy >= (unsigned)NWID) continue;
        const bfu* rb = rowb + (long)dy * NWID * CIN;
        f16x2 w1[3][4], w2[3][4];
        #pragma unroll
        for (int t = 0; t < 3; ++t) {
            const bfu* wp = wT + (size_t)((dy + 1) * 3 + t) * CIN + c8;
            H8 wa; wa.u = *(const uint4*)wp;
            H8 wb; wb.u = *(const uint4*)(wp + 512);
            #pragma unroll
            for (int q = 0; q < 4; ++q) { w1[t][q] = wa.h[q]; w2[t][q] = wb.h[q]; }
        }
        #pragma unroll
        for (int c = 0; c < 10; ++c) {
            int xx = x0 - 1 + c;
            if ((unsigned)xx >= (unsigned)NWID) continue;
            H8 v1; v1.u = *(const uint4*)(rb + (size_t)xx * CIN);
            H8 v2; v2.u = *(const uint4*)(rb + (size_t)xx * CIN + 512);
            #pragma unroll
            for (int j = 0; j < 8; ++j) {
                int t = c - j;
                if (t < 0 || t > 2) continue;
                #pragma unroll
                for (int q = 0; q < 4; ++q) {
                    a1[j][q] = w1[t][q] * v1.h[q] + a1[j][q];
                    a2[j][q] = w2[t][q] * v2.h[q] + a2[j][q];
                }
            }
        }
    }
    #pragma unroll
    for (int j = 0; j < 8; ++j) {
        H8 o;
        #pragma unroll
        for (int q = 0; q < 4; ++q) {
            float g0 = gelu_tanh((float)a1[j][q][0]) * (float)a2[j][q][0];
            float g1 = gelu_tanh((float)a1[j][q][1]) * (float)a2[j][q][1];
            f16x2 r; r[0] = (_Float16)g0; r[1] = (_Float16)g1;
            o.h[q] = r;
        }
        *(uint4*)(out + ((size_t)b * NHW + (size_t)y * NWID + x0 + j) * COUT + c8) = o.u;
    }
}

// ---------------------------------------------------------------------------
// MFMA Gram (fp16). grid (64 n-chunks, CB). 4 waves x 2 heads each.
// ---------------------------------------------------------------------------
__global__ __launch_bounds__(256) void gram_pm(
    const bfu* __restrict__ qkv, float* __restrict__ S32,
    float* __restrict__ Q2, float* __restrict__ K2, int b0)
{
    __shared__ bfu lds[392 * 72];
    const int b = blockIdx.y;
    const int nc = blockIdx.x;
    const int tid = threadIdx.x;
    const int lane = tid & 63, wave = tid >> 6;
    const int l15 = lane & 15, kg = lane >> 4;

    f32x4 sAcc[2][2][2], qAcc[2][2], kAcc[2][2];
    #pragma unroll
    for (int h = 0; h < 2; ++h)
        #pragma unroll
        for (int i = 0; i < 2; ++i) {
            qAcc[h][i] = (f32x4){0.f, 0.f, 0.f, 0.f};
            kAcc[h][i] = (f32x4){0.f, 0.f, 0.f, 0.f};
            #pragma unroll
            for (int j = 0; j < 2; ++j) sAcc[h][i][j] = (f32x4){0.f, 0.f, 0.f, 0.f};
        }

    const size_t pbase = (size_t)b * NHW + (size_t)nc * 256;
    unsigned* ldsw = (unsigned*)lds;

    for (int it = 0; it < 4; ++it) {
        const size_t nb = pbase + it * 64;
        #pragma unroll
        for (int i = 0; i < 6; ++i) {
            int task = i * 256 + tid;
            int np = task & 31, ch = task >> 5;
            const bfu* r0 = qkv + (nb + np * 2) * CQKV + ch * 8;
            uint4 v0 = *(const uint4*)r0;
            uint4 v1 = *(const uint4*)(r0 + CQKV);
            int cb8 = ch * 8;
            ldsw[(cb8 + 0) * 36 + np] = (v0.x & 0xffffu) | (v1.x << 16);
            ldsw[(cb8 + 1) * 36 + np] = (v0.x >> 16) | (v1.x & 0xffff0000u);
            ldsw[(cb8 + 2) * 36 + np] = (v0.y & 0xffffu) | (v1.y << 16);
            ldsw[(cb8 + 3) * 36 + np] = (v0.y >> 16) | (v1.y & 0xffff0000u);
            ldsw[(cb8 + 4) * 36 + np] = (v0.z & 0xffffu) | (v1.z << 16);
            ldsw[(cb8 + 5) * 36 + np] = (v0.z >> 16) | (v1.z & 0xffff0000u);
            ldsw[(cb8 + 6) * 36 + np] = (v0.w & 0xffffu) | (v1.w << 16);
            ldsw[(cb8 + 7) * 36 + np] = (v0.w >> 16) | (v1.w & 0xffff0000u);
        }
        ldsw[(384 + (tid >> 5)) * 36 + (tid & 31)] = 0;
        __syncthreads();
        #pragma unroll
        for (int hh = 0; hh < 2; ++hh) {
            const int h = wave * 2 + hh;
            const int qr = h * NCF, kr = NC + h * NCF;
            #pragma unroll
            for (int ks = 0; ks < 2; ++ks) {
                const int nsub = ks * 32 + kg * 8;
                f16x8 aq0 = *(const f16x8*)(lds + (qr + l15) * 72 + nsub);
                f16x8 aq1 = *(const f16x8*)(lds + (qr + 16 + l15) * 72 + nsub);
                f16x8 bk0 = *(const f16x8*)(lds + (kr + l15) * 72 + nsub);
                f16x8 bk1 = *(const f16x8*)(lds + (kr + 16 + l15) * 72 + nsub);
                sAcc[hh][0][0] = __builtin_amdgcn_mfma_f32_16x16x32_f16(aq0, bk0, sAcc[hh][0][0], 0, 0, 0);
                sAcc[hh][0][1] = __builtin_amdgcn_mfma_f32_16x16x32_f16(aq0, bk1, sAcc[hh][0][1], 0, 0, 0);
                sAcc[hh][1][0] = __builtin_amdgcn_mfma_f32_16x16x32_f16(aq1, bk0, sAcc[hh][1][0], 0, 0, 0);
                sAcc[hh][1][1] = __builtin_amdgcn_mfma_f32_16x16x32_f16(aq1, bk1, sAcc[hh][1][1], 0, 0, 0);
                qAcc[hh][0] = __builtin_amdgcn_mfma_f32_16x16x32_f16(aq0, aq0, qAcc[hh][0], 0, 0, 0);
                qAcc[hh][1] = __builtin_amdgcn_mfma_f32_16x16x32_f16(aq1, aq1, qAcc[hh][1], 0, 0, 0);
                kAcc[hh][0] = __builtin_amdgcn_mfma_f32_16x16x32_f16(bk0, bk0, kAcc[hh][0], 0, 0, 0);
                kAcc[hh][1] = __builtin_amdgcn_mfma_f32_16x16x32_f16(bk1, bk1, kAcc[hh][1], 0, 0, 0);
            }
        }
        __syncthreads();
    }

    const int gb = b0 + b;
    #pragma unroll
    for (int hh = 0; hh < 2; ++hh) {
        const int h = wave * 2 + hh;
        float* Sp = S32 + ((size_t)gb * NHEADS + h) * 1024;
        #pragma unroll
        for (int mt = 0; mt < 2; ++mt)
            #pragma unroll
            for (int nt = 0; nt < 2; ++nt)
                #pragma unroll
                for (int r = 0; r < 4; ++r) {
                    int c = mt * 16 + kg * 4 + r, d = nt * 16 + l15;
                    atomicAdd(&Sp[c * 32 + d], sAcc[hh][mt][nt][r]);
                }
        #pragma unroll
        for (int t = 0; t < 2; ++t)
            #pragma unroll
            for (int r = 0; r < 4; ++r) {
                int row = t * 16 + kg * 4 + r, col = t * 16 + l15;
                if (row == col && row < NCF) {
                    atomicAdd(&Q2[((size_t)gb * NHEADS + h) * NCF + row], qAcc[hh][t][r]);
                    atomicAdd(&K2[((size_t)gb * NHEADS + h) * NCF + row], kAcc[hh][t][r]);
                }
            }
    }
}

// ---------------------------------------------------------------------------
// normalize -> softmax -> fold proj_w -> Mbf packed-fragment fp16. grid(CB)
// ---------------------------------------------------------------------------
__global__ __launch_bounds__(256) void attn_fold(
    const float* __restrict__ S32, const float* __restrict__ Q2, const float* __restrict__ K2,
    const float* __restrict__ temp, const float* __restrict__ projw, bfu* __restrict__ Mbf, int b0)
{
    const int gb = b0 + blockIdx.x, tid = threadIdx.x;
    __shared__ float P[NHEADS * NCF * NCF];
    for (int e = tid; e < NHEADS * NCF * NCF; e += 256) {
        int h = e / (NCF * NCF);
        int r = e % (NCF * NCF);
        int c = r / NCF, d = r % NCF;
        float sv = S32[((size_t)gb * NHEADS + h) * 1024 + c * 32 + d];
        float rq = sqrtf(Q2[((size_t)gb * NHEADS + h) * NCF + c]);
        float rk = sqrtf(K2[((size_t)gb * NHEADS + h) * NCF + d]);
        P[e] = sv / (rq * rk) * temp[h];
    }
    __syncthreads();
    if (tid < NHEADS * NCF) {
        int h = tid / NCF, c = tid % NCF;
        float* row = P + h * (NCF * NCF) + c * NCF;
        float mx = row[0];
        #pragma unroll
        for (int d = 1; d < NCF; ++d) mx = fmaxf(mx, row[d]);
        float sum = 0.f;
        #pragma unroll
        for (int d = 0; d < NCF; ++d) { float e2 = __expf(row[d] - mx); row[d] = e2; sum += e2; }
        float inv = 1.f / sum;
        #pragma unroll
        for (int d = 0; d < NCF; ++d) row[d] *= inv;
    }
    __syncthreads();
    bfu* Mb = Mbf + (size_t)gb * OM_PAD * NC;
    if (tid < NC) {
        int o = tid;
        int o16 = o >> 4, l15o = o & 15;
        for (int h = 0; h < NHEADS; ++h) {
            float pw[NCF];
            #pragma unroll
            for (int c = 0; c < NCF; ++c) pw[c] = projw[(size_t)o * NC + h * NCF + c];
            #pragma unroll
            for (int d = 0; d < NCF; ++d) {
                float acc = 0.f;
                #pragma unroll
                for (int c = 0; c < NCF; ++c) acc = fmaf(pw[c], P[h * (NCF * NCF) + c * NCF + d], acc);
                int cc = h * NCF + d;
                int idx = (o16 * 6 + (cc >> 5)) * 512 + ((cc >> 3) & 3) * 128 + l15o * 8 + (cc & 7);
                Mb[idx] = f2h(acc);
            }
        }
    }
    for (int e = tid; e < (OM_PAD - NC) * NC; e += 256) Mb[NC * NC + e] = 0;
}

// ---------------------------------------------------------------------------
extern "C" void kernel_launch(void* const* d_in, const int* in_sizes, int n_in,
                              void* d_out, int out_size, void* d_ws, size_t ws_size,
                              hipStream_t stream)
{
    const float* x     = (const float*)d_in[0];
    const float* kv    = (const float*)d_in[1];
    const float* ln1w  = (const float*)d_in[2];
    const float* ln1b  = (const float*)d_in[3];
    const float* akern = (const float*)d_in[4];
    const float* qkvw  = (const float*)d_in[5];
    const float* qkvdw = (const float*)d_in[6];
    const float* projw = (const float*)d_in[7];
    const float* temp  = (const float*)d_in[8];
    const float* ln2w  = (const float*)d_in[9];
    const float* ln2b  = (const float*)d_in[10];
    const float* fkern = (const float*)d_in[11];
    const float* pinw  = (const float*)d_in[12];
    const float* ffndw = (const float*)d_in[13];
    const float* poutw = (const float*)d_in[14];
    float* out = (float*)d_out;

    char* wp = (char*)d_ws;
    size_t off = 0;
    auto take = [&](size_t bytes) {
        char* r = wp + off;
        off = (off + bytes + 255) & ~(size_t)255;
        return r;
    };
    float* s1 = (float*)take(NB * NC * 4);  float* t1 = (float*)take(NB * NC * 4);
    float* s2 = (float*)take(NB * NC * 4);  float* t2 = (float*)take(NB * NC * 4);
    bfu* A1 = (bfu*)take((size_t)NB * OQKV_PAD * 192 * 2);
    bfu* A2 = (bfu*)take((size_t)NB * CPIN * 192 * 2);
    bfu* A3 = (bfu*)take((size_t)OM_PAD * 512 * 2);
    bfu* Mbf = (bfu*)take((size_t)NB * OM_PAD * NC * 2);
    float* u1  = (float*)take((size_t)NB * OQKV_PAD * 4);
    float* v01 = (float*)take((size_t)NB * OQKV_PAD * 4);
    float* u2  = (float*)take((size_t)NB * CPIN * 4);
    float* v02 = (float*)take((size_t)NB * CPIN * 4);
    bfu* wdwT1 = (bfu*)take(9 * CQKV * 2);
    bfu* wdwT2 = (bfu*)take(9 * CPIN * 2);
    float* S32 = (float*)take((size_t)NB * NHEADS * 1024 * 4);
    float* Q2  = (float*)take((size_t)NB * NHEADS * NCF * 4);
    float* K2  = (float*)take((size_t)NB * NHEADS * NCF * 4);
    const size_t bigoff = off;

    const size_t PB = (size_t)NHW * (384 + 384 + 2048 + 1152);
    size_t avail = (ws_size > bigoff) ? ws_size - bigoff : 0;
    int CB = 8;
    while (CB > 1 && (size_t)CB * PB > avail) CB >>= 1;

    dim3 blk(256);

    prep_film<<<dim3(48, NB), blk, 0, stream>>>(kv, akern, ln1w, ln1b, s1, t1);
    prep_film<<<dim3(48, NB), blk, 0, stream>>>(kv, fkern, ln2w, ln2b, s2, t2);
    wprep<<<dim3(OQKV_PAD / 4, NB), blk, 0, stream>>>(qkvw, s1, t1, A1, u1, v01, 0);
    wprep<<<dim3(CPIN / 4, NB), blk, 0, stream>>>(pinw, s2, t2, A2, u2, v02, 1);
    wprep<<<dim3(OM_PAD / 4, 1), blk, 0, stream>>>(poutw, s1, t1, A3, nullptr, nullptr, 2);
    wdw_prep<<<(9 * CQKV + 255) / 256, blk, 0, stream>>>(qkvdw, wdwT1, CQKV, 0);
    wdw_prep<<<(9 * CPIN + 255) / 256, blk, 0, stream>>>(ffndw, wdwT2, CPIN, 1);
    {
        int nz = NB * NHEADS * 1024 + 2 * NB * NHEADS * NCF + 256;
        zfill<<<(nz + 255) / 256, blk, 0, stream>>>(S32, nz);
    }

    for (int b0 = 0; b0 < NB; b0 += CB) {
        bfu* bfX  = (bfu*)(wp + bigoff);
        bfu* out1 = (bfu*)(wp + bigoff + (size_t)CB * NHW * 384);
        char* big1 = wp + bigoff + (size_t)CB * NHW * 768;
        char* big2 = big1 + (size_t)CB * NHW * 2048;
        bfu* qkv_pre = (bfu*)big1;
        bfu* qkvb    = (bfu*)big2;
        bfu* u_pre   = (bfu*)big1;
        bfu* gbuf    = (bfu*)big2;

        const float* xb = x + (size_t)b0 * NC * NHW;

        // ---- attention branch ----
        ln_cvt_cm<<<CB * 256, blk, 0, stream>>>(xb, bfX, CB);
        gemm_pm<0><<<dim3(128, OQKV_PAD / 128, CB), blk, 0, stream>>>(
            A1 + (size_t)b0 * OQKV_PAD * 192, (long)OQKV_PAD * 192, OQKV_PAD, CQKV, 192,
            bfX, NC, 0, qkv_pre, CQKV, nullptr, 0,
            u1 + (size_t)b0 * OQKV_PAD, v01 + (size_t)b0 * OQKV_PAD, OQKV_PAD);
        dw_pm8x2<CQKV><<<CB * 288, blk, 0, stream>>>(qkv_pre, wdwT1, qkvb, CB);
        gram_pm<<<dim3(64, CB), blk, 0, stream>>>(qkvb, S32, Q2, K2, b0);
        attn_fold<<<CB, blk, 0, stream>>>(S32, Q2, K2, temp, projw, Mbf, b0);
        // out1(fp16) = bfX + M @ v
        gemm_pm<1><<<dim3(128, OM_PAD / 128, CB), blk, 0, stream>>>(
            Mbf + (size_t)b0 * OM_PAD * NC, (long)OM_PAD * NC, OM_PAD, NC, 192,
            qkvb, CQKV, 384, out1, NC, bfX, NC,
            nullptr, nullptr, 0);

        // ---- FFN branch ----
        gemm_pm<0><<<dim3(128, CPIN / 128, CB), blk, 0, stream>>>(
            A2 + (size_t)b0 * CPIN * 192, (long)CPIN * 192, CPIN, CPIN, 192,
            out1, NC, 0, u_pre, CPIN, nullptr, 0,
            u2 + (size_t)b0 * CPIN, v02 + (size_t)b0 * CPIN, CPIN);
        dw_gate8<CPIN, CG><<<CB * 512, blk, 0, stream>>>(u_pre, wdwT2, gbuf, CB);
        // d_out (f32 channel-major) = out1 + pout @ g, written directly
        gemm_pm<3><<<dim3(256, OM_PAD / 128, CB), blk, 0, stream>>>(
            A3, 0, OM_PAD, NC, 512,
            gbuf, CG, 0, out + (size_t)b0 * NC * NHW, 0, out1, NC,
            nullptr, nullptr, 0);
    }
}

// Round 14
// 720.082 us; speedup vs baseline: 1.2196x; 1.0443x over previous
//
#include <hip/hip_runtime.h>
#include <math.h>

#define NB 8
#define NC 192
#define NHEADS 8
#define NCF 24
#define NHW 16384
#define NWID 128
#define CQKV 576
#define OQKV_PAD 640
#define CPIN 1024
#define CG 512
#define OM_PAD 256

typedef unsigned short bfu;                 // fp16 bit patterns
typedef _Float16 f16x8 __attribute__((ext_vector_type(8)));
typedef _Float16 f16x2 __attribute__((ext_vector_type(2)));
typedef float f32x4 __attribute__((ext_vector_type(4)));

__device__ __forceinline__ unsigned short f2h(float f) {
    _Float16 h = (_Float16)f;
    return __builtin_bit_cast(unsigned short, h);
}
__device__ __forceinline__ float h2f(unsigned short u) {
    return (float)__builtin_bit_cast(_Float16, u);
}
__device__ __forceinline__ float gelu_tanh(float x) {
    float x3 = x * x * x;
    float z = 0.7978845608028654f * fmaf(0.044715f, x3, x);
    float e = __expf(2.f * z);
    float th = 1.f - 2.f / (e + 1.f);
    return 0.5f * x * (1.f + th);
}

struct F8 { float v[8]; };
union H8 { uint4 u; f16x2 h[4]; };
__device__ __forceinline__ F8 loadh8(const bfu* p) {
    uint4 r = *(const uint4*)p;
    F8 o;
    o.v[0] = h2f((unsigned short)(r.x & 0xffff)); o.v[1] = h2f((unsigned short)(r.x >> 16));
    o.v[2] = h2f((unsigned short)(r.y & 0xffff)); o.v[3] = h2f((unsigned short)(r.y >> 16));
    o.v[4] = h2f((unsigned short)(r.z & 0xffff)); o.v[5] = h2f((unsigned short)(r.z >> 16));
    o.v[6] = h2f((unsigned short)(r.w & 0xffff)); o.v[7] = h2f((unsigned short)(r.w >> 16));
    return o;
}
__device__ __forceinline__ void storeh8(bfu* p, const float* a) {
    uint4 r;
    r.x = (unsigned)f2h(a[0]) | ((unsigned)f2h(a[1]) << 16);
    r.y = (unsigned)f2h(a[2]) | ((unsigned)f2h(a[3]) << 16);
    r.z = (unsigned)f2h(a[4]) | ((unsigned)f2h(a[5]) << 16);
    r.w = (unsigned)f2h(a[6]) | ((unsigned)f2h(a[7]) << 16);
    *(uint4*)p = r;
}
__device__ __forceinline__ f16x2 h2z() {
    f16x2 z; z[0] = (_Float16)0.f; z[1] = (_Float16)0.f; return z;
}
// bijective chunked XCD remap (gridDim.x % 8 == 0)
__device__ __forceinline__ int xcd_swz(int bid, int nblk) {
    return (bid & 7) * (nblk >> 3) + (bid >> 3);
}

__global__ __launch_bounds__(256) void zfill(float* __restrict__ p, int n) {
    int i = blockIdx.x * 256 + threadIdx.x;
    if (i < n) p[i] = 0.f;
}

// ---------------------------------------------------------------------------
// prep_film, wave-parallel. grid (48, NB) x 256.
// ---------------------------------------------------------------------------
__global__ __launch_bounds__(256) void prep_film(
    const float* __restrict__ kv, const float* __restrict__ kern,
    const float* __restrict__ lnw, const float* __restrict__ lnb,
    float* __restrict__ sArr, float* __restrict__ tArr)
{
    const int b = blockIdx.y;
    const int wave = threadIdx.x >> 6, lane = threadIdx.x & 63;
    const int r = blockIdx.x * 4 + wave;
    const float* kvb = kv + b * 256;
    float4 kvv = *(const float4*)(kvb + lane * 4);
    float4 k1 = *(const float4*)(kern + (size_t)r * 256 + lane * 4);
    float4 k2 = *(const float4*)(kern + (size_t)(r + NC) * 256 + lane * 4);
    float d1 = kvv.x * k1.x + kvv.y * k1.y + kvv.z * k1.z + kvv.w * k1.w;
    float d2 = kvv.x * k2.x + kvv.y * k2.y + kvv.z * k2.z + kvv.w * k2.w;
    #pragma unroll
    for (int off = 32; off; off >>= 1) {
        d1 += __shfl_down(d1, off, 64);
        d2 += __shfl_down(d2, off, 64);
    }
    if (lane == 0) {
        sArr[b * NC + r] = lnw[r] * d1;
        tArr[b * NC + r] = lnb[r] * d1 + d2;
    }
}

// ---------------------------------------------------------------------------
// Build fp16 A in MFMA-fragment-packed layout + u, v0. Wave-per-row.
// ---------------------------------------------------------------------------
__global__ __launch_bounds__(256) void wprep(
    const float* __restrict__ W, const float* __restrict__ sA, const float* __restrict__ tA,
    bfu* __restrict__ Abf, float* __restrict__ u, float* __restrict__ v0, int mode)
{
    const int wave = threadIdx.x >> 6, lane = threadIdx.x & 63;
    const int o = blockIdx.x * 4 + wave;
    const int b = blockIdx.y;
    const int Opad = (mode == 0) ? OQKV_PAD : (mode == 1 ? CPIN : OM_PAD);
    const int K = (mode == 2) ? 512 : 192;
    const int Kr = (mode == 2) ? 510 : 192;
    const int K32 = K >> 5;
    int src;
    if (mode == 0) src = (o < 576) ? o : -1;
    else if (mode == 1) src = (o < 510) ? o : (o < 512 ? -1 : (o < 1022 ? o - 2 : -1));
    else src = (o < 192) ? o : -1;
    const float* wr = (src >= 0) ? W + (size_t)src * Kr : nullptr;
    const float* sb = sA + b * NC;
    const float* tb = tA + b * NC;
    bfu* abase = Abf + (size_t)b * Opad * K;
    float au = 0.f, av = 0.f;
    for (int c0 = lane * 4; c0 < K; c0 += 256) {
        float a[4] = {0.f, 0.f, 0.f, 0.f};
        if (src >= 0) {
            #pragma unroll
            for (int j = 0; j < 4; ++j) {
                int c = c0 + j;
                if (c < Kr) {
                    float w = wr[c];
                    if (mode == 2) a[j] = w;
                    else { a[j] = w * sb[c]; av = fmaf(w, tb[c], av); }
                }
            }
        }
        ushort4 pk;
        bfu b0 = f2h(a[0]), b1 = f2h(a[1]), b2 = f2h(a[2]), b3 = f2h(a[3]);
        pk.x = b0; pk.y = b1; pk.z = b2; pk.w = b3;
        au += h2f(b0) + h2f(b1) + h2f(b2) + h2f(b3);
        int frag = (o >> 4) * K32 + (c0 >> 5);
        int within = ((c0 >> 3) & 3) * 128 + (o & 15) * 8 + (c0 & 7);
        *(ushort4*)(abase + (size_t)frag * 512 + within) = pk;
    }
    if (mode < 2) {
        #pragma unroll
        for (int off = 32; off; off >>= 1) {
            au += __shfl_down(au, off, 64);
            av += __shfl_down(av, off, 64);
        }
        if (lane == 0) {
            u[(size_t)b * Opad + o] = au;
            v0[(size_t)b * Opad + o] = (src >= 0) ? av : 0.f;
        }
    }
}

// transpose dw weights to fp16
__global__ __launch_bounds__(256) void wdw_prep(
    const float* __restrict__ src, bfu* __restrict__ dstT, int C, int mode)
{
    int i = blockIdx.x * 256 + threadIdx.x;
    if (i >= 9 * C) return;
    int tap = i / C, col = i % C;
    float v;
    if (mode == 0) v = src[(size_t)col * 9 + tap];
    else {
        if (col < 512) v = (col < 510) ? src[(size_t)col * 9 + tap] : 0.f;
        else { int c2 = col - 512; v = (c2 < 510) ? src[(size_t)(510 + c2) * 9 + tap] : 0.f; }
    }
    dstT[(size_t)tap * C + col] = f2h(v);
}

// ---------------------------------------------------------------------------
// fp16 convert only: channel-major fp32 -> pixel-major fp16 via LDS transpose.
// ---------------------------------------------------------------------------
__global__ __launch_bounds__(256) void ln_cvt_cm(
    const float* __restrict__ x, bfu* __restrict__ xbf, int cb)
{
    __shared__ bfu lt[64][198];
    const int blkpx = blockIdx.x;
    const int b = blkpx >> 8;
    const int n0 = (blkpx & 255) * 64;
    const int tid = threadIdx.x;
    #pragma unroll
    for (int it = 0; it < 12; ++it) {
        int task = it * 256 + tid;
        int c = task >> 4, q = task & 15;
        float4 v = *(const float4*)(x + ((size_t)b * NC + c) * NHW + n0 + q * 4);
        lt[q * 4 + 0][c] = f2h(v.x);
        lt[q * 4 + 1][c] = f2h(v.y);
        lt[q * 4 + 2][c] = f2h(v.z);
        lt[q * 4 + 3][c] = f2h(v.w);
    }
    __syncthreads();
    #pragma unroll
    for (int it = 0; it < 6; ++it) {
        int task = it * 256 + tid;
        int px = task / 24, ckk = task % 24;
        const unsigned* row = (const unsigned*)&lt[px][0];
        uint4 o;
        o.x = row[ckk * 4 + 0]; o.y = row[ckk * 4 + 1];
        o.z = row[ckk * 4 + 2]; o.w = row[ckk * 4 + 3];
        *(uint4*)(xbf + ((size_t)b * NHW + n0 + px) * NC + ckk * 8) = o;
    }
}

// ---------------------------------------------------------------------------
// MFMA GEMM (fp16), A fragment-packed.
// EPI 0/1 (K=192): tile 128o x 128px, single-stage full-K LDS (pitch 200).
//   EPI 0 computes LN stats IN-KERNEL from the staged tile.
// EPI 3 (K=512): tile 128o x 64px, BK=64 double-buffered; f32 channel-major out.
// ---------------------------------------------------------------------------
template<int EPI>
__global__ __launch_bounds__(256) void gemm_pm(
    const bfu* __restrict__ A, long aBStride, int Opad, int Oreal, int K,
    const bfu* __restrict__ X, int xRow, int xOff,
    void* __restrict__ Y, int yRow,
    const void* __restrict__ res, int resRow,
    const float* __restrict__ uvec, const float* __restrict__ v0vec, int uStride)
{
    constexpr bool FULLK = (EPI != 3);
    constexpr int SMEMSZ = FULLK ? (128 * 200 * 2 + 128 * 8) : 33024;
    __shared__ __align__(16) char smem[SMEMSZ];
    bfu* xs = (bfu*)smem;
    bfu (*stg)[136] = (bfu(*)[136])smem;
    float (*stg32)[129] = (float(*)[129])smem;
    float* smu = (float*)(smem + 128 * 200 * 2);
    float* srs = smu + 128;

    const int b = blockIdx.z;
    const int om = blockIdx.y * 128;
    const int tid = threadIdx.x;
    const int lane = tid & 63, wave = tid >> 6;
    const int wy = wave >> 1, wx = wave & 1;
    const int l15 = lane & 15, kg = lane >> 4;
    const int K32 = K >> 5;
    const int o16b = (om >> 4) + wy * 4;
    const bfu* Ab = A + (size_t)b * aBStride;

    if constexpr (FULLK) {
        const int n0 = blockIdx.x * 128;
        const bfu* Xbase = X + ((size_t)b * NHW + n0) * xRow + xOff;

        f32x4 acc[4][4];
        #pragma unroll
        for (int i = 0; i < 4; ++i)
            #pragma unroll
            for (int j = 0; j < 4; ++j) acc[i][j] = (f32x4){0.f, 0.f, 0.f, 0.f};

        #pragma unroll
        for (int i = 0; i < 12; ++i) {
            int task = i * 256 + tid;
            int r = task / 24, c = task % 24;
            uint4 v = *(const uint4*)(Xbase + (size_t)r * xRow + c * 8);
            *(uint4*)&xs[r * 200 + c * 8] = v;
        }
        __syncthreads();

        if (EPI == 0) {
            int px = tid >> 1, hh = tid & 1;
            float s = 0.f, ss = 0.f;
            #pragma unroll
            for (int i = 0; i < 12; ++i) {
                F8 v = loadh8(xs + px * 200 + hh * 96 + i * 8);
                #pragma unroll
                for (int j = 0; j < 8; ++j) { s += v.v[j]; ss = fmaf(v.v[j], v.v[j], ss); }
            }
            s += __shfl_xor(s, 1, 64);
            ss += __shfl_xor(ss, 1, 64);
            if (hh == 0) {
                float m = s * (1.f / 192.f);
                float var = ss * (1.f / 192.f) - m * m;
                smu[px] = m;
                srs[px] = rsqrtf(var + 1e-5f);
            }
        }

        #pragma unroll
        for (int k32 = 0; k32 < 6; ++k32) {
            f16x8 af[4], bfr[4];
            #pragma unroll
            for (int mf = 0; mf < 4; ++mf)
                af[mf] = *(const f16x8*)(Ab + ((size_t)(o16b + mf) * 6 + k32) * 512 + lane * 8);
            #pragma unroll
            for (int nf = 0; nf < 4; ++nf)
                bfr[nf] = *(const f16x8*)&xs[(wx * 64 + nf * 16 + l15) * 200 + k32 * 32 + kg * 8];
            #pragma unroll
            for (int mf = 0; mf < 4; ++mf)
                #pragma unroll
                for (int nf = 0; nf < 4; ++nf)
                    acc[mf][nf] = __builtin_amdgcn_mfma_f32_16x16x32_f16(af[mf], bfr[nf], acc[mf][nf], 0, 0, 0);
        }
        __syncthreads();

        #pragma unroll
        for (int nf = 0; nf < 4; ++nf) {
            const int nl = wx * 64 + nf * 16 + l15;
            float muv = 0.f, rsv = 0.f;
            if (EPI == 0) { muv = smu[nl]; rsv = srs[nl]; }
            #pragma unroll
            for (int mf = 0; mf < 4; ++mf) {
                const int obl = wy * 64 + mf * 16 + kg * 4;
                float r0, r1, r2, r3;
                if (EPI == 0) {
                    float4 uv = *(const float4*)(uvec + (size_t)b * uStride + om + obl);
                    float4 vv = *(const float4*)(v0vec + (size_t)b * uStride + om + obl);
                    r0 = rsv * (acc[mf][nf][0] - muv * uv.x) + vv.x;
                    r1 = rsv * (acc[mf][nf][1] - muv * uv.y) + vv.y;
                    r2 = rsv * (acc[mf][nf][2] - muv * uv.z) + vv.z;
                    r3 = rsv * (acc[mf][nf][3] - muv * uv.w) + vv.w;
                } else {
                    r0 = acc[mf][nf][0]; r1 = acc[mf][nf][1];
                    r2 = acc[mf][nf][2]; r3 = acc[mf][nf][3];
                }
                ushort4 pk;
                pk.x = f2h(r0); pk.y = f2h(r1); pk.z = f2h(r2); pk.w = f2h(r3);
                *(ushort4*)&stg[nl][obl] = pk;
            }
        }
        __syncthreads();

        #pragma unroll
        for (int it = 0; it < 8; ++it) {
            int task = it * 256 + tid;
            int nl = task >> 4, ch = task & 15;
            int oc = om + ch * 8;
            if (oc >= Oreal) continue;
            uint4 sv = *(const uint4*)&stg[nl][ch * 8];
            size_t nglob = (size_t)b * NHW + n0 + nl;
            if (EPI == 0) {
                *(uint4*)((bfu*)Y + nglob * yRow + oc) = sv;
            } else {
                float a[8];
                a[0] = h2f((unsigned short)(sv.x & 0xffff)); a[1] = h2f((unsigned short)(sv.x >> 16));
                a[2] = h2f((unsigned short)(sv.y & 0xffff)); a[3] = h2f((unsigned short)(sv.y >> 16));
                a[4] = h2f((unsigned short)(sv.z & 0xffff)); a[5] = h2f((unsigned short)(sv.z >> 16));
                a[6] = h2f((unsigned short)(sv.w & 0xffff)); a[7] = h2f((unsigned short)(sv.w >> 16));
                F8 rv = loadh8((const bfu*)res + nglob * resRow + oc);
                #pragma unroll
                for (int j = 0; j < 8; ++j) a[j] += rv.v[j];
                storeh8((bfu*)Y + nglob * yRow + oc, a);
            }
        }
    } else {
        const int n0 = blockIdx.x * 64;
        const bfu* Xbase = X + ((size_t)b * NHW + n0) * xRow + xOff;
        const int sr = tid >> 3, sc = tid & 7;
        const int NCH = K >> 6;

        f32x4 acc[4][2];
        #pragma unroll
        for (int i = 0; i < 4; ++i)
            #pragma unroll
            for (int j = 0; j < 2; ++j) acc[i][j] = (f32x4){0.f, 0.f, 0.f, 0.f};

        #pragma unroll
        for (int i = 0; i < 2; ++i) {
            int r = i * 32 + sr;
            uint4 v = *(const uint4*)(Xbase + (size_t)r * xRow + sc * 8);
            *(uint4*)&xs[r * 72 + sc * 8] = v;
        }
        __syncthreads();
        for (int kc = 0; kc < NCH; ++kc) {
            const int cur = kc & 1;
            if (kc + 1 < NCH) {
                #pragma unroll
                for (int i = 0; i < 2; ++i) {
                    int r = i * 32 + sr;
                    uint4 v = *(const uint4*)(Xbase + (size_t)r * xRow + (kc + 1) * 64 + sc * 8);
                    *(uint4*)&xs[((cur ^ 1) * 64 + r) * 72 + sc * 8] = v;
                }
            }
            #pragma unroll
            for (int ks = 0; ks < 2; ++ks) {
                const int k32 = kc * 2 + ks;
                f16x8 af[4], bfr[2];
                #pragma unroll
                for (int mf = 0; mf < 4; ++mf)
                    af[mf] = *(const f16x8*)(Ab + ((size_t)(o16b + mf) * K32 + k32) * 512 + lane * 8);
                #pragma unroll
                for (int nf = 0; nf < 2; ++nf)
                    bfr[nf] = *(const f16x8*)&xs[(cur * 64 + wx * 32 + nf * 16 + l15) * 72 + ks * 32 + kg * 8];
                #pragma unroll
                for (int mf = 0; mf < 4; ++mf)
                    #pragma unroll
                    for (int nf = 0; nf < 2; ++nf)
                        acc[mf][nf] = __builtin_amdgcn_mfma_f32_16x16x32_f16(af[mf], bfr[nf], acc[mf][nf], 0, 0, 0);
            }
            __syncthreads();
        }

        #pragma unroll
        for (int nf = 0; nf < 2; ++nf) {
            const int nl = wx * 32 + nf * 16 + l15;
            #pragma unroll
            for (int mf = 0; mf < 4; ++mf) {
                const int obl = wy * 64 + mf * 16 + kg * 4;
                stg32[nl][obl + 0] = acc[mf][nf][0];
                stg32[nl][obl + 1] = acc[mf][nf][1];
                stg32[nl][obl + 2] = acc[mf][nf][2];
                stg32[nl][obl + 3] = acc[mf][nf][3];
            }
        }
        __syncthreads();

        #pragma unroll
        for (int it = 0; it < 8; ++it) {
            int task = it * 256 + tid;
            int o = task >> 4, q = task & 15;
            int oc = om + o;
            if (oc >= Oreal) continue;
            float vals[4];
            #pragma unroll
            for (int j = 0; j < 4; ++j) {
                float v = stg32[q * 4 + j][o];
                float r = h2f(((const bfu*)res)[((size_t)b * NHW + n0 + q * 4 + j) * resRow + oc]);
                vals[j] = v + r;
            }
            *(float4*)((float*)Y + ((size_t)b * NC + oc) * NHW + n0 + q * 4) =
                make_float4(vals[0], vals[1], vals[2], vals[3]);
        }
    }
}

// ---------------------------------------------------------------------------
// depthwise 3x3, fp16 packed math, thread = 8ch x 8px x 2 ROWS, XCD-swizzled.
// ---------------------------------------------------------------------------
template<int CIN>
__global__ __launch_bounds__(256) void dw_pm8x2(
    const bfu* __restrict__ in, const bfu* __restrict__ wT, bfu* __restrict__ out, int cb)
{
    const int CHUNKS = CIN / 8;
    const int UNITS = NHW / 16;
    const int wid = xcd_swz(blockIdx.x, gridDim.x);
    int f = wid * 256 + threadIdx.x;
    if (f >= cb * UNITS * CHUNKS) return;
    int ch = f % CHUNKS;
    int pu = f / CHUNKS;
    int u = pu % UNITS;
    int b = pu / UNITS;
    int xq = u & 15, yh = u >> 4;
    int x0 = xq * 8, y0 = yh * 2;
    const int c8 = ch * 8;
    const bfu* base = in + ((size_t)b * NHW) * CIN + c8;

    f16x2 w[9][4];
    #pragma unroll
    for (int t = 0; t < 9; ++t) {
        H8 wv; wv.u = *(const uint4*)(wT + (size_t)t * CIN + c8);
        #pragma unroll
        for (int q = 0; q < 4; ++q) w[t][q] = wv.h[q];
    }

    f16x2 acc[2][8][4];
    #pragma unroll
    for (int oy = 0; oy < 2; ++oy)
        #pragma unroll
        for (int j = 0; j < 8; ++j)
            #pragma unroll
            for (int q = 0; q < 4; ++q) acc[oy][j][q] = h2z();

    #pragma unroll
    for (int ry = 0; ry < 4; ++ry) {
        int yy = y0 - 1 + ry;
        if ((unsigned)yy >= (unsigned)NWID) continue;
        const bfu* rb = base + (size_t)yy * NWID * CIN;
        #pragma unroll
        for (int c = 0; c < 10; ++c) {
            int xx = x0 - 1 + c;
            if ((unsigned)xx >= (unsigned)NWID) continue;
            H8 v; v.u = *(const uint4*)(rb + (size_t)xx * CIN);
            #pragma unroll
            for (int oy = 0; oy < 2; ++oy) {
                int rt = ry - oy;
                if (rt < 0 || rt > 2) continue;
                #pragma unroll
                for (int j = 0; j < 8; ++j) {
                    int tx = c - j;
                    if (tx < 0 || tx > 2) continue;
                    #pragma unroll
                    for (int q = 0; q < 4; ++q)
                        acc[oy][j][q] = w[rt * 3 + tx][q] * v.h[q] + acc[oy][j][q];
                }
            }
        }
    }
    #pragma unroll
    for (int oy = 0; oy < 2; ++oy) {
        #pragma unroll
        for (int j = 0; j < 8; ++j) {
            H8 o;
            #pragma unroll
            for (int q = 0; q < 4; ++q) o.h[q] = acc[oy][j][q];
            *(uint4*)(out + ((size_t)b * NHW + (size_t)(y0 + oy) * NWID + x0 + j) * CIN + c8) = o.u;
        }
    }
}

// ---------------------------------------------------------------------------
// depthwise 3x3 + GELU gate, fp16 packed math, thread = 8ch x 8px, XCD-swz.
// ---------------------------------------------------------------------------
template<int CIN, int COUT>
__global__ __launch_bounds__(256) void dw_gate8(
    const bfu* __restrict__ in, const bfu* __restrict__ wT, bfu* __restrict__ out, int cb)
{
    const int CHUNKS = COUT / 8;
    const int NPB = NHW / 8;
    const int wid = xcd_swz(blockIdx.x, gridDim.x);
    int f = wid * 256 + threadIdx.x;
    if (f >= cb * NPB * CHUNKS) return;
    int ch = f % CHUNKS;
    int pb = f / CHUNKS;
    int n8 = pb & (NPB - 1);
    int b  = pb >> 11;
    int xq = n8 & 15, y = n8 >> 4;
    int x0 = xq * 8;
    const int c8 = ch * 8;
    const bfu* rowb = in + ((size_t)b * NHW + (size_t)y * NWID) * CIN + c8;

    f16x2 a1[8][4], a2[8][4];
    #pragma unroll
    for (int j = 0; j < 8; ++j)
        #pragma unroll
        for (int q = 0; q < 4; ++q) { a1[j][q] = h2z(); a2[j][q] = h2z(); }

    #pragma unroll
    for (int dy = -1; dy <= 1; ++dy) {
        int yy = y + dy;
        if ((unsigned)yy >= (unsigned)NWID) continue;
        const bfu* rb = rowb + (long)dy * NWID * CIN;
        f16x2 w1[3][4], w2[3][4];
        #pragma unroll
        for (int t = 0; t < 3; ++t) {
            const bfu* wp = wT + (size_t)((dy + 1) * 3 + t) * CIN + c8;
            H8 wa; wa.u = *(const uint4*)wp;
            H8 wb; wb.u = *(const uint4*)(wp + 512);
            #pragma unroll
            for (int q = 0; q < 4; ++q) { w1[t][q] = wa.h[q]; w2[t][q] = wb.h[q]; }
        }
        #pragma unroll
        for (int c = 0; c < 10; ++c) {
            int xx = x0 - 1 + c;
            if ((unsigned)xx >= (unsigned)NWID) continue;
            H8 v1; v1.u = *(const uint4*)(rb + (size_t)xx * CIN);
            H8 v2; v2.u = *(const uint4*)(rb + (size_t)xx * CIN + 512);
            #pragma unroll
            for (int j = 0; j < 8; ++j) {
                int t = c - j;
                if (t < 0 || t > 2) continue;
                #pragma unroll
                for (int q = 0; q < 4; ++q) {
                    a1[j][q] = w1[t][q] * v1.h[q] + a1[j][q];
                    a2[j][q] = w2[t][q] * v2.h[q] + a2[j][q];
                }
            }
        }
    }
    #pragma unroll
    for (int j = 0; j < 8; ++j) {
        H8 o;
        #pragma unroll
        for (int q = 0; q < 4; ++q) {
            float g0 = gelu_tanh((float)a1[j][q][0]) * (float)a2[j][q][0];
            float g1 = gelu_tanh((float)a1[j][q][1]) * (float)a2[j][q][1];
            f16x2 r; r[0] = (_Float16)g0; r[1] = (_Float16)g1;
            o.h[q] = r;
        }
        *(uint4*)(out + ((size_t)b * NHW + (size_t)y * NWID + x0 + j) * COUT + c8) = o.u;
    }
}

// ---------------------------------------------------------------------------
// MFMA Gram (fp16). grid (64 n-chunks, CB). 4 waves x 2 heads each.
// ---------------------------------------------------------------------------
__global__ __launch_bounds__(256) void gram_pm(
    const bfu* __restrict__ qkv, float* __restrict__ S32,
    float* __restrict__ Q2, float* __restrict__ K2, int b0)
{
    __shared__ bfu lds[392 * 72];
    const int b = blockIdx.y;
    const int nc = blockIdx.x;
    const int tid = threadIdx.x;
    const int lane = tid & 63, wave = tid >> 6;
    const int l15 = lane & 15, kg = lane >> 4;

    f32x4 sAcc[2][2][2], qAcc[2][2], kAcc[2][2];
    #pragma unroll
    for (int h = 0; h < 2; ++h)
        #pragma unroll
        for (int i = 0; i < 2; ++i) {
            qAcc[h][i] = (f32x4){0.f, 0.f, 0.f, 0.f};
            kAcc[h][i] = (f32x4){0.f, 0.f, 0.f, 0.f};
            #pragma unroll
            for (int j = 0; j < 2; ++j) sAcc[h][i][j] = (f32x4){0.f, 0.f, 0.f, 0.f};
        }

    const size_t pbase = (size_t)b * NHW + (size_t)nc * 256;
    unsigned* ldsw = (unsigned*)lds;

    for (int it = 0; it < 4; ++it) {
        const size_t nb = pbase + it * 64;
        #pragma unroll
        for (int i = 0; i < 6; ++i) {
            int task = i * 256 + tid;
            int np = task & 31, ch = task >> 5;
            const bfu* r0 = qkv + (nb + np * 2) * CQKV + ch * 8;
            uint4 v0 = *(const uint4*)r0;
            uint4 v1 = *(const uint4*)(r0 + CQKV);
            int cb8 = ch * 8;
            ldsw[(cb8 + 0) * 36 + np] = (v0.x & 0xffffu) | (v1.x << 16);
            ldsw[(cb8 + 1) * 36 + np] = (v0.x >> 16) | (v1.x & 0xffff0000u);
            ldsw[(cb8 + 2) * 36 + np] = (v0.y & 0xffffu) | (v1.y << 16);
            ldsw[(cb8 + 3) * 36 + np] = (v0.y >> 16) | (v1.y & 0xffff0000u);
            ldsw[(cb8 + 4) * 36 + np] = (v0.z & 0xffffu) | (v1.z << 16);
            ldsw[(cb8 + 5) * 36 + np] = (v0.z >> 16) | (v1.z & 0xffff0000u);
            ldsw[(cb8 + 6) * 36 + np] = (v0.w & 0xffffu) | (v1.w << 16);
            ldsw[(cb8 + 7) * 36 + np] = (v0.w >> 16) | (v1.w & 0xffff0000u);
        }
        ldsw[(384 + (tid >> 5)) * 36 + (tid & 31)] = 0;
        __syncthreads();
        #pragma unroll
        for (int hh = 0; hh < 2; ++hh) {
            const int h = wave * 2 + hh;
            const int qr = h * NCF, kr = NC + h * NCF;
            #pragma unroll
            for (int ks = 0; ks < 2; ++ks) {
                const int nsub = ks * 32 + kg * 8;
                f16x8 aq0 = *(const f16x8*)(lds + (qr + l15) * 72 + nsub);
                f16x8 aq1 = *(const f16x8*)(lds + (qr + 16 + l15) * 72 + nsub);
                f16x8 bk0 = *(const f16x8*)(lds + (kr + l15) * 72 + nsub);
                f16x8 bk1 = *(const f16x8*)(lds + (kr + 16 + l15) * 72 + nsub);
                sAcc[hh][0][0] = __builtin_amdgcn_mfma_f32_16x16x32_f16(aq0, bk0, sAcc[hh][0][0], 0, 0, 0);
                sAcc[hh][0][1] = __builtin_amdgcn_mfma_f32_16x16x32_f16(aq0, bk1, sAcc[hh][0][1], 0, 0, 0);
                sAcc[hh][1][0] = __builtin_amdgcn_mfma_f32_16x16x32_f16(aq1, bk0, sAcc[hh][1][0], 0, 0, 0);
                sAcc[hh][1][1] = __builtin_amdgcn_mfma_f32_16x16x32_f16(aq1, bk1, sAcc[hh][1][1], 0, 0, 0);
                qAcc[hh][0] = __builtin_amdgcn_mfma_f32_16x16x32_f16(aq0, aq0, qAcc[hh][0], 0, 0, 0);
                qAcc[hh][1] = __builtin_amdgcn_mfma_f32_16x16x32_f16(aq1, aq1, qAcc[hh][1], 0, 0, 0);
                kAcc[hh][0] = __builtin_amdgcn_mfma_f32_16x16x32_f16(bk0, bk0, kAcc[hh][0], 0, 0, 0);
                kAcc[hh][1] = __builtin_amdgcn_mfma_f32_16x16x32_f16(bk1, bk1, kAcc[hh][1], 0, 0, 0);
            }
        }
        __syncthreads();
    }

    const int gb = b0 + b;
    #pragma unroll
    for (int hh = 0; hh < 2; ++hh) {
        const int h = wave * 2 + hh;
        float* Sp = S32 + ((size_t)gb * NHEADS + h) * 1024;
        #pragma unroll
        for (int mt = 0; mt < 2; ++mt)
            #pragma unroll
            for (int nt = 0; nt < 2; ++nt)
                #pragma unroll
                for (int r = 0; r < 4; ++r) {
                    int c = mt * 16 + kg * 4 + r, d = nt * 16 + l15;
                    atomicAdd(&Sp[c * 32 + d], sAcc[hh][mt][nt][r]);
                }
        #pragma unroll
        for (int t = 0; t < 2; ++t)
            #pragma unroll
            for (int r = 0; r < 4; ++r) {
                int row = t * 16 + kg * 4 + r, col = t * 16 + l15;
                if (row == col && row < NCF) {
                    atomicAdd(&Q2[((size_t)gb * NHEADS + h) * NCF + row], qAcc[hh][t][r]);
                    atomicAdd(&K2[((size_t)gb * NHEADS + h) * NCF + row], kAcc[hh][t][r]);
                }
            }
    }
}

// ---------------------------------------------------------------------------
// normalize -> softmax -> fold proj_w -> Mbf packed-fragment fp16. grid(CB)
// ---------------------------------------------------------------------------
__global__ __launch_bounds__(256) void attn_fold(
    const float* __restrict__ S32, const float* __restrict__ Q2, const float* __restrict__ K2,
    const float* __restrict__ temp, const float* __restrict__ projw, bfu* __restrict__ Mbf, int b0)
{
    const int gb = b0 + blockIdx.x, tid = threadIdx.x;
    __shared__ float P[NHEADS * NCF * NCF];
    for (int e = tid; e < NHEADS * NCF * NCF; e += 256) {
        int h = e / (NCF * NCF);
        int r = e % (NCF * NCF);
        int c = r / NCF, d = r % NCF;
        float sv = S32[((size_t)gb * NHEADS + h) * 1024 + c * 32 + d];
        float rq = sqrtf(Q2[((size_t)gb * NHEADS + h) * NCF + c]);
        float rk = sqrtf(K2[((size_t)gb * NHEADS + h) * NCF + d]);
        P[e] = sv / (rq * rk) * temp[h];
    }
    __syncthreads();
    if (tid < NHEADS * NCF) {
        int h = tid / NCF, c = tid % NCF;
        float* row = P + h * (NCF * NCF) + c * NCF;
        float mx = row[0];
        #pragma unroll
        for (int d = 1; d < NCF; ++d) mx = fmaxf(mx, row[d]);
        float sum = 0.f;
        #pragma unroll
        for (int d = 0; d < NCF; ++d) { float e2 = __expf(row[d] - mx); row[d] = e2; sum += e2; }
        float inv = 1.f / sum;
        #pragma unroll
        for (int d = 0; d < NCF; ++d) row[d] *= inv;
    }
    __syncthreads();
    bfu* Mb = Mbf + (size_t)gb * OM_PAD * NC;
    if (tid < NC) {
        int o = tid;
        int o16 = o >> 4, l15o = o & 15;
        for (int h = 0; h < NHEADS; ++h) {
            float pw[NCF];
            #pragma unroll
            for (int c = 0; c < NCF; ++c) pw[c] = projw[(size_t)o * NC + h * NCF + c];
            #pragma unroll
            for (int d = 0; d < NCF; ++d) {
                float acc = 0.f;
                #pragma unroll
                for (int c = 0; c < NCF; ++c) acc = fmaf(pw[c], P[h * (NCF * NCF) + c * NCF + d], acc);
                int cc = h * NCF + d;
                int idx = (o16 * 6 + (cc >> 5)) * 512 + ((cc >> 3) & 3) * 128 + l15o * 8 + (cc & 7);
                Mb[idx] = f2h(acc);
            }
        }
    }
    for (int e = tid; e < (OM_PAD - NC) * NC; e += 256) Mb[NC * NC + e] = 0;
}

// ---------------------------------------------------------------------------
extern "C" void kernel_launch(void* const* d_in, const int* in_sizes, int n_in,
                              void* d_out, int out_size, void* d_ws, size_t ws_size,
                              hipStream_t stream)
{
    const float* x     = (const float*)d_in[0];
    const float* kv    = (const float*)d_in[1];
    const float* ln1w  = (const float*)d_in[2];
    const float* ln1b  = (const float*)d_in[3];
    const float* akern = (const float*)d_in[4];
    const float* qkvw  = (const float*)d_in[5];
    const float* qkvdw = (const float*)d_in[6];
    const float* projw = (const float*)d_in[7];
    const float* temp  = (const float*)d_in[8];
    const float* ln2w  = (const float*)d_in[9];
    const float* ln2b  = (const float*)d_in[10];
    const float* fkern = (const float*)d_in[11];
    const float* pinw  = (const float*)d_in[12];
    const float* ffndw = (const float*)d_in[13];
    const float* poutw = (const float*)d_in[14];
    float* out = (float*)d_out;

    char* wp = (char*)d_ws;
    size_t off = 0;
    auto take = [&](size_t bytes) {
        char* r = wp + off;
        off = (off + bytes + 255) & ~(size_t)255;
        return r;
    };
    float* s1 = (float*)take(NB * NC * 4);  float* t1 = (float*)take(NB * NC * 4);
    float* s2 = (float*)take(NB * NC * 4);  float* t2 = (float*)take(NB * NC * 4);
    bfu* A1 = (bfu*)take((size_t)NB * OQKV_PAD * 192 * 2);
    bfu* A2 = (bfu*)take((size_t)NB * CPIN * 192 * 2);
    bfu* A3 = (bfu*)take((size_t)OM_PAD * 512 * 2);
    bfu* Mbf = (bfu*)take((size_t)NB * OM_PAD * NC * 2);
    float* u1  = (float*)take((size_t)NB * OQKV_PAD * 4);
    float* v01 = (float*)take((size_t)NB * OQKV_PAD * 4);
    float* u2  = (float*)take((size_t)NB * CPIN * 4);
    float* v02 = (float*)take((size_t)NB * CPIN * 4);
    bfu* wdwT1 = (bfu*)take(9 * CQKV * 2);
    bfu* wdwT2 = (bfu*)take(9 * CPIN * 2);
    float* S32 = (float*)take((size_t)NB * NHEADS * 1024 * 4);
    float* Q2  = (float*)take((size_t)NB * NHEADS * NCF * 4);
    float* K2  = (float*)take((size_t)NB * NHEADS * NCF * 4);
    const size_t bigoff = off;

    const size_t PB = (size_t)NHW * (384 + 384 + 2048 + 1152);
    size_t avail = (ws_size > bigoff) ? ws_size - bigoff : 0;
    int CB = 8;
    while (CB > 1 && (size_t)CB * PB > avail) CB >>= 1;

    dim3 blk(256);

    prep_film<<<dim3(48, NB), blk, 0, stream>>>(kv, akern, ln1w, ln1b, s1, t1);
    prep_film<<<dim3(48, NB), blk, 0, stream>>>(kv, fkern, ln2w, ln2b, s2, t2);
    wprep<<<dim3(OQKV_PAD / 4, NB), blk, 0, stream>>>(qkvw, s1, t1, A1, u1, v01, 0);
    wprep<<<dim3(CPIN / 4, NB), blk, 0, stream>>>(pinw, s2, t2, A2, u2, v02, 1);
    wprep<<<dim3(OM_PAD / 4, 1), blk, 0, stream>>>(poutw, s1, t1, A3, nullptr, nullptr, 2);
    wdw_prep<<<(9 * CQKV + 255) / 256, blk, 0, stream>>>(qkvdw, wdwT1, CQKV, 0);
    wdw_prep<<<(9 * CPIN + 255) / 256, blk, 0, stream>>>(ffndw, wdwT2, CPIN, 1);
    {
        int nz = NB * NHEADS * 1024 + 2 * NB * NHEADS * NCF + 256;
        zfill<<<(nz + 255) / 256, blk, 0, stream>>>(S32, nz);
    }

    for (int b0 = 0; b0 < NB; b0 += CB) {
        bfu* bfX  = (bfu*)(wp + bigoff);
        bfu* out1 = (bfu*)(wp + bigoff + (size_t)CB * NHW * 384);
        char* big1 = wp + bigoff + (size_t)CB * NHW * 768;
        char* big2 = big1 + (size_t)CB * NHW * 2048;
        bfu* qkv_pre = (bfu*)big1;
        bfu* qkvb    = (bfu*)big2;
        bfu* u_pre   = (bfu*)big1;
        bfu* gbuf    = (bfu*)big2;

        const float* xb = x + (size_t)b0 * NC * NHW;

        // ---- attention branch ----
        ln_cvt_cm<<<CB * 256, blk, 0, stream>>>(xb, bfX, CB);
        gemm_pm<0><<<dim3(128, OQKV_PAD / 128, CB), blk, 0, stream>>>(
            A1 + (size_t)b0 * OQKV_PAD * 192, (long)OQKV_PAD * 192, OQKV_PAD, CQKV, 192,
            bfX, NC, 0, qkv_pre, CQKV, nullptr, 0,
            u1 + (size_t)b0 * OQKV_PAD, v01 + (size_t)b0 * OQKV_PAD, OQKV_PAD);
        dw_pm8x2<CQKV><<<CB * 288, blk, 0, stream>>>(qkv_pre, wdwT1, qkvb, CB);
        gram_pm<<<dim3(64, CB), blk, 0, stream>>>(qkvb, S32, Q2, K2, b0);
        attn_fold<<<CB, blk, 0, stream>>>(S32, Q2, K2, temp, projw, Mbf, b0);
        // out1(fp16) = bfX + M @ v
        gemm_pm<1><<<dim3(128, OM_PAD / 128, CB), blk, 0, stream>>>(
            Mbf + (size_t)b0 * OM_PAD * NC, (long)OM_PAD * NC, OM_PAD, NC, 192,
            qkvb, CQKV, 384, out1, NC, bfX, NC,
            nullptr, nullptr, 0);

        // ---- FFN branch ----
        gemm_pm<0><<<dim3(128, CPIN / 128, CB), blk, 0, stream>>>(
            A2 + (size_t)b0 * CPIN * 192, (long)CPIN * 192, CPIN, CPIN, 192,
            out1, NC, 0, u_pre, CPIN, nullptr, 0,
            u2 + (size_t)b0 * CPIN, v02 + (size_t)b0 * CPIN, CPIN);
        dw_gate8<CPIN, CG><<<CB * 512, blk, 0, stream>>>(u_pre, wdwT2, gbuf, CB);
        // d_out (f32 channel-major) = out1 + pout @ g, written directly
        gemm_pm<3><<<dim3(256, OM_PAD / 128, CB), blk, 0, stream>>>(
            A3, 0, OM_PAD, NC, 512,
            gbuf, CG, 0, out + (size_t)b0 * NC * NHW, 0, out1, NC,
            nullptr, nullptr, 0);
    }
}

// Round 15
// 710.590 us; speedup vs baseline: 1.2359x; 1.0134x over previous
//
#include <hip/hip_runtime.h>
#include <math.h>

#define NB 8
#define NC 192
#define NHEADS 8
#define NCF 24
#define NHW 16384
#define NWID 128
#define CQKV 576
#define OQKV_PAD 640
#define CPIN 1024
#define CG 512
#define OM_PAD 256

typedef unsigned short bfu;                 // fp16 bit patterns
typedef _Float16 f16x8 __attribute__((ext_vector_type(8)));
typedef _Float16 f16x2 __attribute__((ext_vector_type(2)));
typedef float f32x4 __attribute__((ext_vector_type(4)));

__device__ __forceinline__ unsigned short f2h(float f) {
    _Float16 h = (_Float16)f;
    return __builtin_bit_cast(unsigned short, h);
}
__device__ __forceinline__ float h2f(unsigned short u) {
    return (float)__builtin_bit_cast(_Float16, u);
}
__device__ __forceinline__ float gelu_tanh(float x) {
    float x3 = x * x * x;
    float z = 0.7978845608028654f * fmaf(0.044715f, x3, x);
    float e = __expf(2.f * z);
    float th = 1.f - 2.f / (e + 1.f);
    return 0.5f * x * (1.f + th);
}

struct F8 { float v[8]; };
union H8 { uint4 u; f16x2 h[4]; };
__device__ __forceinline__ F8 loadh8(const bfu* p) {
    uint4 r = *(const uint4*)p;
    F8 o;
    o.v[0] = h2f((unsigned short)(r.x & 0xffff)); o.v[1] = h2f((unsigned short)(r.x >> 16));
    o.v[2] = h2f((unsigned short)(r.y & 0xffff)); o.v[3] = h2f((unsigned short)(r.y >> 16));
    o.v[4] = h2f((unsigned short)(r.z & 0xffff)); o.v[5] = h2f((unsigned short)(r.z >> 16));
    o.v[6] = h2f((unsigned short)(r.w & 0xffff)); o.v[7] = h2f((unsigned short)(r.w >> 16));
    return o;
}
__device__ __forceinline__ void storeh8(bfu* p, const float* a) {
    uint4 r;
    r.x = (unsigned)f2h(a[0]) | ((unsigned)f2h(a[1]) << 16);
    r.y = (unsigned)f2h(a[2]) | ((unsigned)f2h(a[3]) << 16);
    r.z = (unsigned)f2h(a[4]) | ((unsigned)f2h(a[5]) << 16);
    r.w = (unsigned)f2h(a[6]) | ((unsigned)f2h(a[7]) << 16);
    *(uint4*)p = r;
}
__device__ __forceinline__ f16x2 h2z() {
    f16x2 z; z[0] = (_Float16)0.f; z[1] = (_Float16)0.f; return z;
}
// bijective chunked XCD remap (gridDim.x % 8 == 0)
__device__ __forceinline__ int xcd_swz(int bid, int nblk) {
    return (bid & 7) * (nblk >> 3) + (bid >> 3);
}

__global__ __launch_bounds__(256) void zfill(float* __restrict__ p, int n) {
    int i = blockIdx.x * 256 + threadIdx.x;
    if (i < n) p[i] = 0.f;
}

// ---------------------------------------------------------------------------
// prep_film, wave-parallel. grid (48, NB) x 256.
// ---------------------------------------------------------------------------
__global__ __launch_bounds__(256) void prep_film(
    const float* __restrict__ kv, const float* __restrict__ kern,
    const float* __restrict__ lnw, const float* __restrict__ lnb,
    float* __restrict__ sArr, float* __restrict__ tArr)
{
    const int b = blockIdx.y;
    const int wave = threadIdx.x >> 6, lane = threadIdx.x & 63;
    const int r = blockIdx.x * 4 + wave;
    const float* kvb = kv + b * 256;
    float4 kvv = *(const float4*)(kvb + lane * 4);
    float4 k1 = *(const float4*)(kern + (size_t)r * 256 + lane * 4);
    float4 k2 = *(const float4*)(kern + (size_t)(r + NC) * 256 + lane * 4);
    float d1 = kvv.x * k1.x + kvv.y * k1.y + kvv.z * k1.z + kvv.w * k1.w;
    float d2 = kvv.x * k2.x + kvv.y * k2.y + kvv.z * k2.z + kvv.w * k2.w;
    #pragma unroll
    for (int off = 32; off; off >>= 1) {
        d1 += __shfl_down(d1, off, 64);
        d2 += __shfl_down(d2, off, 64);
    }
    if (lane == 0) {
        sArr[b * NC + r] = lnw[r] * d1;
        tArr[b * NC + r] = lnb[r] * d1 + d2;
    }
}

// ---------------------------------------------------------------------------
// Build fp16 A in MFMA-fragment-packed layout + u, v0. Wave-per-row.
// ---------------------------------------------------------------------------
__global__ __launch_bounds__(256) void wprep(
    const float* __restrict__ W, const float* __restrict__ sA, const float* __restrict__ tA,
    bfu* __restrict__ Abf, float* __restrict__ u, float* __restrict__ v0, int mode)
{
    const int wave = threadIdx.x >> 6, lane = threadIdx.x & 63;
    const int o = blockIdx.x * 4 + wave;
    const int b = blockIdx.y;
    const int Opad = (mode == 0) ? OQKV_PAD : (mode == 1 ? CPIN : OM_PAD);
    const int K = (mode == 2) ? 512 : 192;
    const int Kr = (mode == 2) ? 510 : 192;
    const int K32 = K >> 5;
    int src;
    if (mode == 0) src = (o < 576) ? o : -1;
    else if (mode == 1) src = (o < 510) ? o : (o < 512 ? -1 : (o < 1022 ? o - 2 : -1));
    else src = (o < 192) ? o : -1;
    const float* wr = (src >= 0) ? W + (size_t)src * Kr : nullptr;
    const float* sb = sA + b * NC;
    const float* tb = tA + b * NC;
    bfu* abase = Abf + (size_t)b * Opad * K;
    float au = 0.f, av = 0.f;
    for (int c0 = lane * 4; c0 < K; c0 += 256) {
        float a[4] = {0.f, 0.f, 0.f, 0.f};
        if (src >= 0) {
            #pragma unroll
            for (int j = 0; j < 4; ++j) {
                int c = c0 + j;
                if (c < Kr) {
                    float w = wr[c];
                    if (mode == 2) a[j] = w;
                    else { a[j] = w * sb[c]; av = fmaf(w, tb[c], av); }
                }
            }
        }
        ushort4 pk;
        bfu b0 = f2h(a[0]), b1 = f2h(a[1]), b2 = f2h(a[2]), b3 = f2h(a[3]);
        pk.x = b0; pk.y = b1; pk.z = b2; pk.w = b3;
        au += h2f(b0) + h2f(b1) + h2f(b2) + h2f(b3);
        int frag = (o >> 4) * K32 + (c0 >> 5);
        int within = ((c0 >> 3) & 3) * 128 + (o & 15) * 8 + (c0 & 7);
        *(ushort4*)(abase + (size_t)frag * 512 + within) = pk;
    }
    if (mode < 2) {
        #pragma unroll
        for (int off = 32; off; off >>= 1) {
            au += __shfl_down(au, off, 64);
            av += __shfl_down(av, off, 64);
        }
        if (lane == 0) {
            u[(size_t)b * Opad + o] = au;
            v0[(size_t)b * Opad + o] = (src >= 0) ? av : 0.f;
        }
    }
}

// transpose dw weights to fp16
__global__ __launch_bounds__(256) void wdw_prep(
    const float* __restrict__ src, bfu* __restrict__ dstT, int C, int mode)
{
    int i = blockIdx.x * 256 + threadIdx.x;
    if (i >= 9 * C) return;
    int tap = i / C, col = i % C;
    float v;
    if (mode == 0) v = src[(size_t)col * 9 + tap];
    else {
        if (col < 512) v = (col < 510) ? src[(size_t)col * 9 + tap] : 0.f;
        else { int c2 = col - 512; v = (c2 < 510) ? src[(size_t)(510 + c2) * 9 + tap] : 0.f; }
    }
    dstT[(size_t)tap * C + col] = f2h(v);
}

// ---------------------------------------------------------------------------
// fp16 convert only: channel-major fp32 -> pixel-major fp16 via LDS transpose.
// ---------------------------------------------------------------------------
__global__ __launch_bounds__(256) void ln_cvt_cm(
    const float* __restrict__ x, bfu* __restrict__ xbf, int cb)
{
    __shared__ bfu lt[64][198];
    const int blkpx = blockIdx.x;
    const int b = blkpx >> 8;
    const int n0 = (blkpx & 255) * 64;
    const int tid = threadIdx.x;
    #pragma unroll
    for (int it = 0; it < 12; ++it) {
        int task = it * 256 + tid;
        int c = task >> 4, q = task & 15;
        float4 v = *(const float4*)(x + ((size_t)b * NC + c) * NHW + n0 + q * 4);
        lt[q * 4 + 0][c] = f2h(v.x);
        lt[q * 4 + 1][c] = f2h(v.y);
        lt[q * 4 + 2][c] = f2h(v.z);
        lt[q * 4 + 3][c] = f2h(v.w);
    }
    __syncthreads();
    #pragma unroll
    for (int it = 0; it < 6; ++it) {
        int task = it * 256 + tid;
        int px = task / 24, ckk = task % 24;
        const unsigned* row = (const unsigned*)&lt[px][0];
        uint4 o;
        o.x = row[ckk * 4 + 0]; o.y = row[ckk * 4 + 1];
        o.z = row[ckk * 4 + 2]; o.w = row[ckk * 4 + 3];
        *(uint4*)(xbf + ((size_t)b * NHW + n0 + px) * NC + ckk * 8) = o;
    }
}

// ---------------------------------------------------------------------------
// MFMA GEMM (fp16), A fragment-packed.
// EPI 0/1 (K=192): tile 128o x 128px, single-stage full-K LDS (pitch 200).
//   EPI 0 computes LN stats IN-KERNEL from the staged tile.
// EPI 3 (K=512): tile 128o x 64px, BK=64 double-buffered; f32 channel-major out.
// ---------------------------------------------------------------------------
template<int EPI>
__global__ __launch_bounds__(256) void gemm_pm(
    const bfu* __restrict__ A, long aBStride, int Opad, int Oreal, int K,
    const bfu* __restrict__ X, int xRow, int xOff,
    void* __restrict__ Y, int yRow,
    const void* __restrict__ res, int resRow,
    const float* __restrict__ uvec, const float* __restrict__ v0vec, int uStride)
{
    constexpr bool FULLK = (EPI != 3);
    constexpr int SMEMSZ = FULLK ? (128 * 200 * 2 + 128 * 8) : 33024;
    __shared__ __align__(16) char smem[SMEMSZ];
    bfu* xs = (bfu*)smem;
    bfu (*stg)[136] = (bfu(*)[136])smem;
    float (*stg32)[129] = (float(*)[129])smem;
    float* smu = (float*)(smem + 128 * 200 * 2);
    float* srs = smu + 128;

    const int b = blockIdx.z;
    const int om = blockIdx.y * 128;
    const int tid = threadIdx.x;
    const int lane = tid & 63, wave = tid >> 6;
    const int wy = wave >> 1, wx = wave & 1;
    const int l15 = lane & 15, kg = lane >> 4;
    const int K32 = K >> 5;
    const int o16b = (om >> 4) + wy * 4;
    const bfu* Ab = A + (size_t)b * aBStride;

    if constexpr (FULLK) {
        const int n0 = blockIdx.x * 128;
        const bfu* Xbase = X + ((size_t)b * NHW + n0) * xRow + xOff;

        f32x4 acc[4][4];
        #pragma unroll
        for (int i = 0; i < 4; ++i)
            #pragma unroll
            for (int j = 0; j < 4; ++j) acc[i][j] = (f32x4){0.f, 0.f, 0.f, 0.f};

        #pragma unroll
        for (int i = 0; i < 12; ++i) {
            int task = i * 256 + tid;
            int r = task / 24, c = task % 24;
            uint4 v = *(const uint4*)(Xbase + (size_t)r * xRow + c * 8);
            *(uint4*)&xs[r * 200 + c * 8] = v;
        }
        __syncthreads();

        if (EPI == 0) {
            int px = tid >> 1, hh = tid & 1;
            float s = 0.f, ss = 0.f;
            #pragma unroll
            for (int i = 0; i < 12; ++i) {
                F8 v = loadh8(xs + px * 200 + hh * 96 + i * 8);
                #pragma unroll
                for (int j = 0; j < 8; ++j) { s += v.v[j]; ss = fmaf(v.v[j], v.v[j], ss); }
            }
            s += __shfl_xor(s, 1, 64);
            ss += __shfl_xor(ss, 1, 64);
            if (hh == 0) {
                float m = s * (1.f / 192.f);
                float var = ss * (1.f / 192.f) - m * m;
                smu[px] = m;
                srs[px] = rsqrtf(var + 1e-5f);
            }
        }

        #pragma unroll
        for (int k32 = 0; k32 < 6; ++k32) {
            f16x8 af[4], bfr[4];
            #pragma unroll
            for (int mf = 0; mf < 4; ++mf)
                af[mf] = *(const f16x8*)(Ab + ((size_t)(o16b + mf) * 6 + k32) * 512 + lane * 8);
            #pragma unroll
            for (int nf = 0; nf < 4; ++nf)
                bfr[nf] = *(const f16x8*)&xs[(wx * 64 + nf * 16 + l15) * 200 + k32 * 32 + kg * 8];
            #pragma unroll
            for (int mf = 0; mf < 4; ++mf)
                #pragma unroll
                for (int nf = 0; nf < 4; ++nf)
                    acc[mf][nf] = __builtin_amdgcn_mfma_f32_16x16x32_f16(af[mf], bfr[nf], acc[mf][nf], 0, 0, 0);
        }
        __syncthreads();

        #pragma unroll
        for (int nf = 0; nf < 4; ++nf) {
            const int nl = wx * 64 + nf * 16 + l15;
            float muv = 0.f, rsv = 0.f;
            if (EPI == 0) { muv = smu[nl]; rsv = srs[nl]; }
            #pragma unroll
            for (int mf = 0; mf < 4; ++mf) {
                const int obl = wy * 64 + mf * 16 + kg * 4;
                float r0, r1, r2, r3;
                if (EPI == 0) {
                    float4 uv = *(const float4*)(uvec + (size_t)b * uStride + om + obl);
                    float4 vv = *(const float4*)(v0vec + (size_t)b * uStride + om + obl);
                    r0 = rsv * (acc[mf][nf][0] - muv * uv.x) + vv.x;
                    r1 = rsv * (acc[mf][nf][1] - muv * uv.y) + vv.y;
                    r2 = rsv * (acc[mf][nf][2] - muv * uv.z) + vv.z;
                    r3 = rsv * (acc[mf][nf][3] - muv * uv.w) + vv.w;
                } else {
                    r0 = acc[mf][nf][0]; r1 = acc[mf][nf][1];
                    r2 = acc[mf][nf][2]; r3 = acc[mf][nf][3];
                }
                ushort4 pk;
                pk.x = f2h(r0); pk.y = f2h(r1); pk.z = f2h(r2); pk.w = f2h(r3);
                *(ushort4*)&stg[nl][obl] = pk;
            }
        }
        __syncthreads();

        #pragma unroll
        for (int it = 0; it < 8; ++it) {
            int task = it * 256 + tid;
            int nl = task >> 4, ch = task & 15;
            int oc = om + ch * 8;
            if (oc >= Oreal) continue;
            uint4 sv = *(const uint4*)&stg[nl][ch * 8];
            size_t nglob = (size_t)b * NHW + n0 + nl;
            if (EPI == 0) {
                *(uint4*)((bfu*)Y + nglob * yRow + oc) = sv;
            } else {
                float a[8];
                a[0] = h2f((unsigned short)(sv.x & 0xffff)); a[1] = h2f((unsigned short)(sv.x >> 16));
                a[2] = h2f((unsigned short)(sv.y & 0xffff)); a[3] = h2f((unsigned short)(sv.y >> 16));
                a[4] = h2f((unsigned short)(sv.z & 0xffff)); a[5] = h2f((unsigned short)(sv.z >> 16));
                a[6] = h2f((unsigned short)(sv.w & 0xffff)); a[7] = h2f((unsigned short)(sv.w >> 16));
                F8 rv = loadh8((const bfu*)res + nglob * resRow + oc);
                #pragma unroll
                for (int j = 0; j < 8; ++j) a[j] += rv.v[j];
                storeh8((bfu*)Y + nglob * yRow + oc, a);
            }
        }
    } else {
        const int n0 = blockIdx.x * 64;
        const bfu* Xbase = X + ((size_t)b * NHW + n0) * xRow + xOff;
        const int sr = tid >> 3, sc = tid & 7;
        const int NCH = K >> 6;

        f32x4 acc[4][2];
        #pragma unroll
        for (int i = 0; i < 4; ++i)
            #pragma unroll
            for (int j = 0; j < 2; ++j) acc[i][j] = (f32x4){0.f, 0.f, 0.f, 0.f};

        #pragma unroll
        for (int i = 0; i < 2; ++i) {
            int r = i * 32 + sr;
            uint4 v = *(const uint4*)(Xbase + (size_t)r * xRow + sc * 8);
            *(uint4*)&xs[r * 72 + sc * 8] = v;
        }
        __syncthreads();
        for (int kc = 0; kc < NCH; ++kc) {
            const int cur = kc & 1;
            if (kc + 1 < NCH) {
                #pragma unroll
                for (int i = 0; i < 2; ++i) {
                    int r = i * 32 + sr;
                    uint4 v = *(const uint4*)(Xbase + (size_t)r * xRow + (kc + 1) * 64 + sc * 8);
                    *(uint4*)&xs[((cur ^ 1) * 64 + r) * 72 + sc * 8] = v;
                }
            }
            #pragma unroll
            for (int ks = 0; ks < 2; ++ks) {
                const int k32 = kc * 2 + ks;
                f16x8 af[4], bfr[2];
                #pragma unroll
                for (int mf = 0; mf < 4; ++mf)
                    af[mf] = *(const f16x8*)(Ab + ((size_t)(o16b + mf) * K32 + k32) * 512 + lane * 8);
                #pragma unroll
                for (int nf = 0; nf < 2; ++nf)
                    bfr[nf] = *(const f16x8*)&xs[(cur * 64 + wx * 32 + nf * 16 + l15) * 72 + ks * 32 + kg * 8];
                #pragma unroll
                for (int mf = 0; mf < 4; ++mf)
                    #pragma unroll
                    for (int nf = 0; nf < 2; ++nf)
                        acc[mf][nf] = __builtin_amdgcn_mfma_f32_16x16x32_f16(af[mf], bfr[nf], acc[mf][nf], 0, 0, 0);
            }
            __syncthreads();
        }

        #pragma unroll
        for (int nf = 0; nf < 2; ++nf) {
            const int nl = wx * 32 + nf * 16 + l15;
            #pragma unroll
            for (int mf = 0; mf < 4; ++mf) {
                const int obl = wy * 64 + mf * 16 + kg * 4;
                stg32[nl][obl + 0] = acc[mf][nf][0];
                stg32[nl][obl + 1] = acc[mf][nf][1];
                stg32[nl][obl + 2] = acc[mf][nf][2];
                stg32[nl][obl + 3] = acc[mf][nf][3];
            }
        }
        __syncthreads();

        #pragma unroll
        for (int it = 0; it < 8; ++it) {
            int task = it * 256 + tid;
            int o = task >> 4, q = task & 15;
            int oc = om + o;
            if (oc >= Oreal) continue;
            float vals[4];
            #pragma unroll
            for (int j = 0; j < 4; ++j) {
                float v = stg32[q * 4 + j][o];
                float r = h2f(((const bfu*)res)[((size_t)b * NHW + n0 + q * 4 + j) * resRow + oc]);
                vals[j] = v + r;
            }
            *(float4*)((float*)Y + ((size_t)b * NC + oc) * NHW + n0 + q * 4) =
                make_float4(vals[0], vals[1], vals[2], vals[3]);
        }
    }
}

// ---------------------------------------------------------------------------
// depthwise 3x3, fp16 packed math, thread = 8ch x 8px x 2 ROWS, XCD-swizzled.
// ---------------------------------------------------------------------------
template<int CIN>
__global__ __launch_bounds__(256) void dw_pm8x2(
    const bfu* __restrict__ in, const bfu* __restrict__ wT, bfu* __restrict__ out, int cb)
{
    const int CHUNKS = CIN / 8;
    const int UNITS = NHW / 16;
    const int wid = xcd_swz(blockIdx.x, gridDim.x);
    int f = wid * 256 + threadIdx.x;
    if (f >= cb * UNITS * CHUNKS) return;
    int ch = f % CHUNKS;
    int pu = f / CHUNKS;
    int u = pu % UNITS;
    int b = pu / UNITS;
    int xq = u & 15, yh = u >> 4;
    int x0 = xq * 8, y0 = yh * 2;
    const int c8 = ch * 8;
    const bfu* base = in + ((size_t)b * NHW) * CIN + c8;

    f16x2 w[9][4];
    #pragma unroll
    for (int t = 0; t < 9; ++t) {
        H8 wv; wv.u = *(const uint4*)(wT + (size_t)t * CIN + c8);
        #pragma unroll
        for (int q = 0; q < 4; ++q) w[t][q] = wv.h[q];
    }

    f16x2 acc[2][8][4];
    #pragma unroll
    for (int oy = 0; oy < 2; ++oy)
        #pragma unroll
        for (int j = 0; j < 8; ++j)
            #pragma unroll
            for (int q = 0; q < 4; ++q) acc[oy][j][q] = h2z();

    #pragma unroll
    for (int ry = 0; ry < 4; ++ry) {
        int yy = y0 - 1 + ry;
        if ((unsigned)yy >= (unsigned)NWID) continue;
        const bfu* rb = base + (size_t)yy * NWID * CIN;
        #pragma unroll
        for (int c = 0; c < 10; ++c) {
            int xx = x0 - 1 + c;
            if ((unsigned)xx >= (unsigned)NWID) continue;
            H8 v; v.u = *(const uint4*)(rb + (size_t)xx * CIN);
            #pragma unroll
            for (int oy = 0; oy < 2; ++oy) {
                int rt = ry - oy;
                if (rt < 0 || rt > 2) continue;
                #pragma unroll
                for (int j = 0; j < 8; ++j) {
                    int tx = c - j;
                    if (tx < 0 || tx > 2) continue;
                    #pragma unroll
                    for (int q = 0; q < 4; ++q)
                        acc[oy][j][q] = w[rt * 3 + tx][q] * v.h[q] + acc[oy][j][q];
                }
            }
        }
    }
    #pragma unroll
    for (int oy = 0; oy < 2; ++oy) {
        #pragma unroll
        for (int j = 0; j < 8; ++j) {
            H8 o;
            #pragma unroll
            for (int q = 0; q < 4; ++q) o.h[q] = acc[oy][j][q];
            *(uint4*)(out + ((size_t)b * NHW + (size_t)(y0 + oy) * NWID + x0 + j) * CIN + c8) = o.u;
        }
    }
}

// ---------------------------------------------------------------------------
// depthwise 3x3 + GELU gate, fp16 packed math, thread = 8ch x 8px, XCD-swz.
// ---------------------------------------------------------------------------
template<int CIN, int COUT>
__global__ __launch_bounds__(256) void dw_gate8(
    const bfu* __restrict__ in, const bfu* __restrict__ wT, bfu* __restrict__ out, int cb)
{
    const int CHUNKS = COUT / 8;
    const int NPB = NHW / 8;
    const int wid = xcd_swz(blockIdx.x, gridDim.x);
    int f = wid * 256 + threadIdx.x;
    if (f >= cb * NPB * CHUNKS) return;
    int ch = f % CHUNKS;
    int pb = f / CHUNKS;
    int n8 = pb & (NPB - 1);
    int b  = pb >> 11;
    int xq = n8 & 15, y = n8 >> 4;
    int x0 = xq * 8;
    const int c8 = ch * 8;
    const bfu* rowb = in + ((size_t)b * NHW + (size_t)y * NWID) * CIN + c8;

    f16x2 a1[8][4], a2[8][4];
    #pragma unroll
    for (int j = 0; j < 8; ++j)
        #pragma unroll
        for (int q = 0; q < 4; ++q) { a1[j][q] = h2z(); a2[j][q] = h2z(); }

    #pragma unroll
    for (int dy = -1; dy <= 1; ++dy) {
        int yy = y + dy;
        if ((unsigned)yy >= (unsigned)NWID) continue;
        const bfu* rb = rowb + (long)dy * NWID * CIN;
        f16x2 w1[3][4], w2[3][4];
        #pragma unroll
        for (int t = 0; t < 3; ++t) {
            const bfu* wp = wT + (size_t)((dy + 1) * 3 + t) * CIN + c8;
            H8 wa; wa.u = *(const uint4*)wp;
            H8 wb; wb.u = *(const uint4*)(wp + 512);
            #pragma unroll
            for (int q = 0; q < 4; ++q) { w1[t][q] = wa.h[q]; w2[t][q] = wb.h[q]; }
        }
        #pragma unroll
        for (int c = 0; c < 10; ++c) {
            int xx = x0 - 1 + c;
            if ((unsigned)xx >= (unsigned)NWID) continue;
            H8 v1; v1.u = *(const uint4*)(rb + (size_t)xx * CIN);
            H8 v2; v2.u = *(const uint4*)(rb + (size_t)xx * CIN + 512);
            #pragma unroll
            for (int j = 0; j < 8; ++j) {
                int t = c - j;
                if (t < 0 || t > 2) continue;
                #pragma unroll
                for (int q = 0; q < 4; ++q) {
                    a1[j][q] = w1[t][q] * v1.h[q] + a1[j][q];
                    a2[j][q] = w2[t][q] * v2.h[q] + a2[j][q];
                }
            }
        }
    }
    #pragma unroll
    for (int j = 0; j < 8; ++j) {
        H8 o;
        #pragma unroll
        for (int q = 0; q < 4; ++q) {
            float g0 = gelu_tanh((float)a1[j][q][0]) * (float)a2[j][q][0];
            float g1 = gelu_tanh((float)a1[j][q][1]) * (float)a2[j][q][1];
            f16x2 r; r[0] = (_Float16)g0; r[1] = (_Float16)g1;
            o.h[q] = r;
        }
        *(uint4*)(out + ((size_t)b * NHW + (size_t)y * NWID + x0 + j) * COUT + c8) = o.u;
    }
}

// ---------------------------------------------------------------------------
// MFMA Gram (fp16). grid (64 n-chunks, CB). 4 waves x 2 heads each.
// ---------------------------------------------------------------------------
__global__ __launch_bounds__(256) void gram_pm(
    const bfu* __restrict__ qkv, float* __restrict__ S32,
    float* __restrict__ Q2, float* __restrict__ K2, int b0)
{
    __shared__ bfu lds[392 * 72];
    const int b = blockIdx.y;
    const int nc = blockIdx.x;
    const int tid = threadIdx.x;
    const int lane = tid & 63, wave = tid >> 6;
    const int l15 = lane & 15, kg = lane >> 4;

    f32x4 sAcc[2][2][2], qAcc[2][2], kAcc[2][2];
    #pragma unroll
    for (int h = 0; h < 2; ++h)
        #pragma unroll
        for (int i = 0; i < 2; ++i) {
            qAcc[h][i] = (f32x4){0.f, 0.f, 0.f, 0.f};
            kAcc[h][i] = (f32x4){0.f, 0.f, 0.f, 0.f};
            #pragma unroll
            for (int j = 0; j < 2; ++j) sAcc[h][i][j] = (f32x4){0.f, 0.f, 0.f, 0.f};
        }

    const size_t pbase = (size_t)b * NHW + (size_t)nc * 256;
    unsigned* ldsw = (unsigned*)lds;

    for (int it = 0; it < 4; ++it) {
        const size_t nb = pbase + it * 64;
        #pragma unroll
        for (int i = 0; i < 6; ++i) {
            int task = i * 256 + tid;
            int np = task & 31, ch = task >> 5;
            const bfu* r0 = qkv + (nb + np * 2) * CQKV + ch * 8;
            uint4 v0 = *(const uint4*)r0;
            uint4 v1 = *(const uint4*)(r0 + CQKV);
            int cb8 = ch * 8;
            ldsw[(cb8 + 0) * 36 + np] = (v0.x & 0xffffu) | (v1.x << 16);
            ldsw[(cb8 + 1) * 36 + np] = (v0.x >> 16) | (v1.x & 0xffff0000u);
            ldsw[(cb8 + 2) * 36 + np] = (v0.y & 0xffffu) | (v1.y << 16);
            ldsw[(cb8 + 3) * 36 + np] = (v0.y >> 16) | (v1.y & 0xffff0000u);
            ldsw[(cb8 + 4) * 36 + np] = (v0.z & 0xffffu) | (v1.z << 16);
            ldsw[(cb8 + 5) * 36 + np] = (v0.z >> 16) | (v1.z & 0xffff0000u);
            ldsw[(cb8 + 6) * 36 + np] = (v0.w & 0xffffu) | (v1.w << 16);
            ldsw[(cb8 + 7) * 36 + np] = (v0.w >> 16) | (v1.w & 0xffff0000u);
        }
        ldsw[(384 + (tid >> 5)) * 36 + (tid & 31)] = 0;
        __syncthreads();
        #pragma unroll
        for (int hh = 0; hh < 2; ++hh) {
            const int h = wave * 2 + hh;
            const int qr = h * NCF, kr = NC + h * NCF;
            #pragma unroll
            for (int ks = 0; ks < 2; ++ks) {
                const int nsub = ks * 32 + kg * 8;
                f16x8 aq0 = *(const f16x8*)(lds + (qr + l15) * 72 + nsub);
                f16x8 aq1 = *(const f16x8*)(lds + (qr + 16 + l15) * 72 + nsub);
                f16x8 bk0 = *(const f16x8*)(lds + (kr + l15) * 72 + nsub);
                f16x8 bk1 = *(const f16x8*)(lds + (kr + 16 + l15) * 72 + nsub);
                sAcc[hh][0][0] = __builtin_amdgcn_mfma_f32_16x16x32_f16(aq0, bk0, sAcc[hh][0][0], 0, 0, 0);
                sAcc[hh][0][1] = __builtin_amdgcn_mfma_f32_16x16x32_f16(aq0, bk1, sAcc[hh][0][1], 0, 0, 0);
                sAcc[hh][1][0] = __builtin_amdgcn_mfma_f32_16x16x32_f16(aq1, bk0, sAcc[hh][1][0], 0, 0, 0);
                sAcc[hh][1][1] = __builtin_amdgcn_mfma_f32_16x16x32_f16(aq1, bk1, sAcc[hh][1][1], 0, 0, 0);
                qAcc[hh][0] = __builtin_amdgcn_mfma_f32_16x16x32_f16(aq0, aq0, qAcc[hh][0], 0, 0, 0);
                qAcc[hh][1] = __builtin_amdgcn_mfma_f32_16x16x32_f16(aq1, aq1, qAcc[hh][1], 0, 0, 0);
                kAcc[hh][0] = __builtin_amdgcn_mfma_f32_16x16x32_f16(bk0, bk0, kAcc[hh][0], 0, 0, 0);
                kAcc[hh][1] = __builtin_amdgcn_mfma_f32_16x16x32_f16(bk1, bk1, kAcc[hh][1], 0, 0, 0);
            }
        }
        __syncthreads();
    }

    const int gb = b0 + b;
    #pragma unroll
    for (int hh = 0; hh < 2; ++hh) {
        const int h = wave * 2 + hh;
        float* Sp = S32 + ((size_t)gb * NHEADS + h) * 1024;
        #pragma unroll
        for (int mt = 0; mt < 2; ++mt)
            #pragma unroll
            for (int nt = 0; nt < 2; ++nt)
                #pragma unroll
                for (int r = 0; r < 4; ++r) {
                    int c = mt * 16 + kg * 4 + r, d = nt * 16 + l15;
                    atomicAdd(&Sp[c * 32 + d], sAcc[hh][mt][nt][r]);
                }
        #pragma unroll
        for (int t = 0; t < 2; ++t)
            #pragma unroll
            for (int r = 0; r < 4; ++r) {
                int row = t * 16 + kg * 4 + r, col = t * 16 + l15;
                if (row == col && row < NCF) {
                    atomicAdd(&Q2[((size_t)gb * NHEADS + h) * NCF + row], qAcc[hh][t][r]);
                    atomicAdd(&K2[((size_t)gb * NHEADS + h) * NCF + row], kAcc[hh][t][r]);
                }
            }
    }
}

// ---------------------------------------------------------------------------
// normalize -> softmax -> fold proj_w -> Mbf packed-fragment fp16. grid(CB)
// ---------------------------------------------------------------------------
__global__ __launch_bounds__(256) void attn_fold(
    const float* __restrict__ S32, const float* __restrict__ Q2, const float* __restrict__ K2,
    const float* __restrict__ temp, const float* __restrict__ projw, bfu* __restrict__ Mbf, int b0)
{
    const int gb = b0 + blockIdx.x, tid = threadIdx.x;
    __shared__ float P[NHEADS * NCF * NCF];
    for (int e = tid; e < NHEADS * NCF * NCF; e += 256) {
        int h = e / (NCF * NCF);
        int r = e % (NCF * NCF);
        int c = r / NCF, d = r % NCF;
        float sv = S32[((size_t)gb * NHEADS + h) * 1024 + c * 32 + d];
        float rq = sqrtf(Q2[((size_t)gb * NHEADS + h) * NCF + c]);
        float rk = sqrtf(K2[((size_t)gb * NHEADS + h) * NCF + d]);
        P[e] = sv / (rq * rk) * temp[h];
    }
    __syncthreads();
    if (tid < NHEADS * NCF) {
        int h = tid / NCF, c = tid % NCF;
        float* row = P + h * (NCF * NCF) + c * NCF;
        float mx = row[0];
        #pragma unroll
        for (int d = 1; d < NCF; ++d) mx = fmaxf(mx, row[d]);
        float sum = 0.f;
        #pragma unroll
        for (int d = 0; d < NCF; ++d) { float e2 = __expf(row[d] - mx); row[d] = e2; sum += e2; }
        float inv = 1.f / sum;
        #pragma unroll
        for (int d = 0; d < NCF; ++d) row[d] *= inv;
    }
    __syncthreads();
    bfu* Mb = Mbf + (size_t)gb * OM_PAD * NC;
    if (tid < NC) {
        int o = tid;
        int o16 = o >> 4, l15o = o & 15;
        for (int h = 0; h < NHEADS; ++h) {
            float pw[NCF];
            #pragma unroll
            for (int c = 0; c < NCF; ++c) pw[c] = projw[(size_t)o * NC + h * NCF + c];
            #pragma unroll
            for (int d = 0; d < NCF; ++d) {
                float acc = 0.f;
                #pragma unroll
                for (int c = 0; c < NCF; ++c) acc = fmaf(pw[c], P[h * (NCF * NCF) + c * NCF + d], acc);
                int cc = h * NCF + d;
                int idx = (o16 * 6 + (cc >> 5)) * 512 + ((cc >> 3) & 3) * 128 + l15o * 8 + (cc & 7);
                Mb[idx] = f2h(acc);
            }
        }
    }
    for (int e = tid; e < (OM_PAD - NC) * NC; e += 256) Mb[NC * NC + e] = 0;
}

// ---------------------------------------------------------------------------
extern "C" void kernel_launch(void* const* d_in, const int* in_sizes, int n_in,
                              void* d_out, int out_size, void* d_ws, size_t ws_size,
                              hipStream_t stream)
{
    const float* x     = (const float*)d_in[0];
    const float* kv    = (const float*)d_in[1];
    const float* ln1w  = (const float*)d_in[2];
    const float* ln1b  = (const float*)d_in[3];
    const float* akern = (const float*)d_in[4];
    const float* qkvw  = (const float*)d_in[5];
    const float* qkvdw = (const float*)d_in[6];
    const float* projw = (const float*)d_in[7];
    const float* temp  = (const float*)d_in[8];
    const float* ln2w  = (const float*)d_in[9];
    const float* ln2b  = (const float*)d_in[10];
    const float* fkern = (const float*)d_in[11];
    const float* pinw  = (const float*)d_in[12];
    const float* ffndw = (const float*)d_in[13];
    const float* poutw = (const float*)d_in[14];
    float* out = (float*)d_out;

    char* wp = (char*)d_ws;
    size_t off = 0;
    auto take = [&](size_t bytes) {
        char* r = wp + off;
        off = (off + bytes + 255) & ~(size_t)255;
        return r;
    };
    float* s1 = (float*)take(NB * NC * 4);  float* t1 = (float*)take(NB * NC * 4);
    float* s2 = (float*)take(NB * NC * 4);  float* t2 = (float*)take(NB * NC * 4);
    bfu* A1 = (bfu*)take((size_t)NB * OQKV_PAD * 192 * 2);
    bfu* A2 = (bfu*)take((size_t)NB * CPIN * 192 * 2);
    bfu* A3 = (bfu*)take((size_t)OM_PAD * 512 * 2);
    bfu* Mbf = (bfu*)take((size_t)NB * OM_PAD * NC * 2);
    float* u1  = (float*)take((size_t)NB * OQKV_PAD * 4);
    float* v01 = (float*)take((size_t)NB * OQKV_PAD * 4);
    float* u2  = (float*)take((size_t)NB * CPIN * 4);
    float* v02 = (float*)take((size_t)NB * CPIN * 4);
    bfu* wdwT1 = (bfu*)take(9 * CQKV * 2);
    bfu* wdwT2 = (bfu*)take(9 * CPIN * 2);
    float* S32 = (float*)take((size_t)NB * NHEADS * 1024 * 4);
    float* Q2  = (float*)take((size_t)NB * NHEADS * NCF * 4);
    float* K2  = (float*)take((size_t)NB * NHEADS * NCF * 4);
    const size_t bigoff = off;

    // per-batch big buffers (aliased):
    //   out1: 384 B/px (own region, lives across both branches)
    //   big1: 2048 B/px -- attention: qkv_pre (1152) + bfX (384, at offset 1152)
    //                      FFN:       u_pre (2048) [qkv_pre/bfX dead by then]
    //   big2: 1152 B/px -- attention: qkvb (1152); FFN: gbuf (1024)
    const size_t PB = (size_t)NHW * (384 + 2048 + 1152);
    size_t avail = (ws_size > bigoff) ? ws_size - bigoff : 0;
    int CB = 8;
    while (CB > 1 && (size_t)CB * PB > avail) CB >>= 1;

    dim3 blk(256);

    prep_film<<<dim3(48, NB), blk, 0, stream>>>(kv, akern, ln1w, ln1b, s1, t1);
    prep_film<<<dim3(48, NB), blk, 0, stream>>>(kv, fkern, ln2w, ln2b, s2, t2);
    wprep<<<dim3(OQKV_PAD / 4, NB), blk, 0, stream>>>(qkvw, s1, t1, A1, u1, v01, 0);
    wprep<<<dim3(CPIN / 4, NB), blk, 0, stream>>>(pinw, s2, t2, A2, u2, v02, 1);
    wprep<<<dim3(OM_PAD / 4, 1), blk, 0, stream>>>(poutw, s1, t1, A3, nullptr, nullptr, 2);
    wdw_prep<<<(9 * CQKV + 255) / 256, blk, 0, stream>>>(qkvdw, wdwT1, CQKV, 0);
    wdw_prep<<<(9 * CPIN + 255) / 256, blk, 0, stream>>>(ffndw, wdwT2, CPIN, 1);
    {
        int nz = NB * NHEADS * 1024 + 2 * NB * NHEADS * NCF + 256;
        zfill<<<(nz + 255) / 256, blk, 0, stream>>>(S32, nz);
    }

    for (int b0 = 0; b0 < NB; b0 += CB) {
        bfu* out1 = (bfu*)(wp + bigoff);
        char* big1 = wp + bigoff + (size_t)CB * NHW * 384;
        char* big2 = big1 + (size_t)CB * NHW * 2048;
        bfu* qkv_pre = (bfu*)big1;
        bfu* bfX     = (bfu*)(big1 + (size_t)CB * NHW * 1152);
        bfu* u_pre   = (bfu*)big1;
        bfu* qkvb    = (bfu*)big2;
        bfu* gbuf    = (bfu*)big2;

        const float* xb = x + (size_t)b0 * NC * NHW;

        // ---- attention branch ----
        ln_cvt_cm<<<CB * 256, blk, 0, stream>>>(xb, bfX, CB);
        gemm_pm<0><<<dim3(128, OQKV_PAD / 128, CB), blk, 0, stream>>>(
            A1 + (size_t)b0 * OQKV_PAD * 192, (long)OQKV_PAD * 192, OQKV_PAD, CQKV, 192,
            bfX, NC, 0, qkv_pre, CQKV, nullptr, 0,
            u1 + (size_t)b0 * OQKV_PAD, v01 + (size_t)b0 * OQKV_PAD, OQKV_PAD);
        dw_pm8x2<CQKV><<<CB * 288, blk, 0, stream>>>(qkv_pre, wdwT1, qkvb, CB);
        gram_pm<<<dim3(64, CB), blk, 0, stream>>>(qkvb, S32, Q2, K2, b0);
        attn_fold<<<CB, blk, 0, stream>>>(S32, Q2, K2, temp, projw, Mbf, b0);
        // out1(fp16) = bfX + M @ v
        gemm_pm<1><<<dim3(128, OM_PAD / 128, CB), blk, 0, stream>>>(
            Mbf + (size_t)b0 * OM_PAD * NC, (long)OM_PAD * NC, OM_PAD, NC, 192,
            qkvb, CQKV, 384, out1, NC, bfX, NC,
            nullptr, nullptr, 0);

        // ---- FFN branch ----
        gemm_pm<0><<<dim3(128, CPIN / 128, CB), blk, 0, stream>>>(
            A2 + (size_t)b0 * CPIN * 192, (long)CPIN * 192, CPIN, CPIN, 192,
            out1, NC, 0, u_pre, CPIN, nullptr, 0,
            u2 + (size_t)b0 * CPIN, v02 + (size_t)b0 * CPIN, CPIN);
        dw_gate8<CPIN, CG><<<CB * 512, blk, 0, stream>>>(u_pre, wdwT2, gbuf, CB);
        // d_out (f32 channel-major) = out1 + pout @ g, written directly
        gemm_pm<3><<<dim3(256, OM_PAD / 128, CB), blk, 0, stream>>>(
            A3, 0, OM_PAD, NC, 512,
            gbuf, CG, 0, out + (size_t)b0 * NC * NHW, 0, out1, NC,
            nullptr, nullptr, 0);
    }
}